// Round 1
// baseline (658.162 us; speedup 1.0000x reference)
//
#include <hip/hip_runtime.h>
#include <stdint.h>
#include <stddef.h>

typedef unsigned short u16;
typedef u16 u16x4 __attribute__((ext_vector_type(4)));
typedef u16 u16x8 __attribute__((ext_vector_type(8)));
typedef __bf16 bf16x8 __attribute__((ext_vector_type(8)));
typedef float f32x4 __attribute__((ext_vector_type(4)));

__device__ __forceinline__ float b2f(u16 u) {
    return __uint_as_float(((unsigned)u) << 16);
}
__device__ __forceinline__ u16 f2b(float f) {
    unsigned u = __float_as_uint(f);
    u += 0x7FFF + ((u >> 16) & 1);   // round-to-nearest-even
    return (u16)(u >> 16);
}
__device__ __forceinline__ bf16x8 bcast(u16x8 v) { return __builtin_bit_cast(bf16x8, v); }
__device__ __forceinline__ f32x4 mfma16(bf16x8 a, bf16x8 b, f32x4 c) {
    return __builtin_amdgcn_mfma_f32_16x16x32_bf16(a, b, c, 0, 0, 0);
}
typedef const __attribute__((address_space(1))) void* gas1;
typedef __attribute__((address_space(3))) void* las3;
__device__ __forceinline__ void gload_lds16(const void* g, void* l) {
    __builtin_amdgcn_global_load_lds((gas1)g, (las3)l, 16, 0, 0);
}

// DPP row_ror:N (rotate within 16-lane row) — VALU cross-lane, no LDS.
#define DPP_ROR_F32(x, N) __builtin_bit_cast(float, __builtin_amdgcn_update_dpp( \
    __builtin_bit_cast(int, (x)), __builtin_bit_cast(int, (x)), 0x120 + (N), 0xf, 0xf, false))
__device__ __forceinline__ float red_max16(float x) {
    x = fmaxf(x, DPP_ROR_F32(x, 8));
    x = fmaxf(x, DPP_ROR_F32(x, 4));
    x = fmaxf(x, DPP_ROR_F32(x, 2));
    x = fmaxf(x, DPP_ROR_F32(x, 1));
    return x;
}
__device__ __forceinline__ float red_add16(float x) {
    x += DPP_ROR_F32(x, 8);
    x += DPP_ROR_F32(x, 4);
    x += DPP_ROR_F32(x, 2);
    x += DPP_ROR_F32(x, 1);
    return x;
}

// ---------------- transpose + f32->bf16: out[C][R] = bf16(in[R][C]) ----------
__global__ __launch_bounds__(256) void transpose_k(const float* __restrict__ in,
                                                   u16* __restrict__ out,
                                                   int R, int C) {
    __shared__ u16 t[32][33];
    int x = blockIdx.x * 32 + threadIdx.x;
    int y0 = blockIdx.y * 32;
#pragma unroll
    for (int j = threadIdx.y; j < 32; j += 8)
        t[j][threadIdx.x] = f2b(in[(size_t)(y0 + j) * C + x]);
    __syncthreads();
    int xo = y0 + threadIdx.x;
    int yo0 = blockIdx.x * 32;
#pragma unroll
    for (int j = threadIdx.y; j < 32; j += 8)
        out[(size_t)(yo0 + j) * R + xo] = t[threadIdx.x][j];
}

// ---------------- layernorm over D=1024, one block per row -------------------
__global__ __launch_bounds__(256) void ln_k(const void* __restrict__ x,
                                            const float* __restrict__ g,
                                            const float* __restrict__ b,
                                            u16* __restrict__ y,
                                            int x_f32) {
    const int row = blockIdx.x;
    const size_t ro = (size_t)row * 1024;
    float v[4], s = 0.0f, ss = 0.0f;
#pragma unroll
    for (int i = 0; i < 4; ++i) {
        size_t idx = ro + threadIdx.x + i * 256;
        float f = x_f32 ? ((const float*)x)[idx] : b2f(((const u16*)x)[idx]);
        v[i] = f; s += f; ss += f * f;
    }
#pragma unroll
    for (int off = 32; off; off >>= 1) {
        s += __shfl_down(s, off);
        ss += __shfl_down(ss, off);
    }
    __shared__ float red[2][4];
    int wave = threadIdx.x >> 6, lane = threadIdx.x & 63;
    if (lane == 0) { red[0][wave] = s; red[1][wave] = ss; }
    __syncthreads();
    s = red[0][0] + red[0][1] + red[0][2] + red[0][3];
    ss = red[1][0] + red[1][1] + red[1][2] + red[1][3];
    float mean = s * (1.0f / 1024.0f);
    float var = ss * (1.0f / 1024.0f) - mean * mean;
    float inv = rsqrtf(var + 1e-5f);
#pragma unroll
    for (int i = 0; i < 4; ++i) {
        int c = threadIdx.x + i * 256;
        float o = (v[i] - mean) * inv * g[c] + b[c];
        y[ro + c] = f2b(o);
    }
}

// ---------------- 256x256 8-phase GEMM core (m201-style template) ------------
// BM=BN=256, BK=64, 512 thr = 8 waves (2Mx4N), per-wave C 128x64 = acc[8][4].
// LDS 128 KiB: A dbuf 2x32 KB @0; B dbuf 2x32 KB @64 KB. Half-tile = 128 rows.
// Swizzle (T2): byte ^= ((row&7)<<4)  [bits 6:4 ^= bits 9:7]; gload_lds writes
// LINEAR dest, global SOURCE is inverse-swizzled (G21).
// Pipeline (T3+T4): per tile t phases stage A1(t+1)@P1, B1(t+1)@P2,
// B0(t+2)@P3, A0(t+2)@P4; t+2 stages are safe because B reads retire at P2 and
// A reads at P3. vmcnt(4) before P4's barrier keeps 2 half-tiles in flight —
// never drained to 0 in the main loop. setprio around MFMA clusters (T5).
__device__ __forceinline__ void gemm256_core(const u16* __restrict__ A,
                                             const u16* __restrict__ Bt,
                                             const int Ksz, const int m0,
                                             const int n0, u16* lds,
                                             f32x4 (&acc)[8][4]) {
    char* ldsb = (char*)lds;
    const int tid = threadIdx.x;
    const int w = tid >> 6, lane = tid & 63;
    const int quad = lane >> 4, l16 = lane & 15;
    const int wr = w >> 2, wc = w & 3;
    // staging: thread covers row rS (+64 on 2nd call), 8 u16 at col cS;
    // source col is swizzle-permuted so a linear LDS write lands swizzled.
    const int rS = w * 8 + (lane >> 3);
    const int cS = ((lane & 7) ^ (lane >> 3)) * 8;
    const int dstW = w * 1024;                       // wave-uniform LDS byte off
    // fragment reads: row = <mult of 16> + l16 -> XOR mask depends on l16 only
    const int xo = (l16 & 7) << 4;
    const int co0 = (quad * 16) ^ xo;                // k-step 0
    const int co1 = (64 + quad * 16) ^ xo;           // k-step 1
    const int aoffB = wr * 16384 + l16 * 128;
    const int boffB = (wc >> 1) * 16384 + (wc & 1) * 8192 + l16 * 128;
    const u16* pA = A + (size_t)(m0 + rS) * Ksz + cS;
    const u16* pB = Bt + (size_t)(n0 + rS) * Ksz + cS;
    const int nK = Ksz >> 6;
    const size_t rstep = (size_t)64 * Ksz;

#define STAGE_A(dd, h, kt) do { \
    const u16* _s = pA + (size_t)((h) * 128) * Ksz + (kt) * 64; \
    char* _d = ldsb + (dd) * 32768 + (h) * 16384 + dstW; \
    gload_lds16(_s, _d); \
    gload_lds16(_s + rstep, _d + 8192); \
} while (0)
#define STAGE_B(dd, h, kt) do { \
    const u16* _s = pB + (size_t)((h) * 128) * Ksz + (kt) * 64; \
    char* _d = ldsb + 65536 + (dd) * 32768 + (h) * 16384 + dstW; \
    gload_lds16(_s, _d); \
    gload_lds16(_s + rstep, _d + 8192); \
} while (0)

    bf16x8 af[2][4], bg[2][2][2];

#define LDA(mh) do { \
    _Pragma("unroll") for (int m4 = 0; m4 < 4; ++m4) { \
        af[0][m4] = bcast(*(const u16x8*)(ldsA + ((mh) * 4 + m4) * 2048 + co0)); \
        af[1][m4] = bcast(*(const u16x8*)(ldsA + ((mh) * 4 + m4) * 2048 + co1)); \
    } \
} while (0)
#define LDB(nh) do { \
    _Pragma("unroll") for (int n2 = 0; n2 < 2; ++n2) { \
        bg[(nh)][0][n2] = bcast(*(const u16x8*)(ldsBp + ((nh) * 2 + n2) * 2048 + co0)); \
        bg[(nh)][1][n2] = bcast(*(const u16x8*)(ldsBp + ((nh) * 2 + n2) * 2048 + co1)); \
    } \
} while (0)
#define QUAD(mh, nh) do { \
    _Pragma("unroll") for (int m4 = 0; m4 < 4; ++m4) \
    _Pragma("unroll") for (int n2 = 0; n2 < 2; ++n2) { \
        acc[(mh) * 4 + m4][(nh) * 2 + n2] = \
            mfma16(af[0][m4], bg[(nh)][0][n2], acc[(mh) * 4 + m4][(nh) * 2 + n2]); \
        acc[(mh) * 4 + m4][(nh) * 2 + n2] = \
            mfma16(af[1][m4], bg[(nh)][1][n2], acc[(mh) * 4 + m4][(nh) * 2 + n2]); \
    } \
} while (0)

    // prologue: all 4 halves of tile 0, then B0(1), A0(1) (the "(t-1) P3/P4")
    STAGE_A(0, 0, 0); STAGE_A(0, 1, 0);
    STAGE_B(0, 0, 0); STAGE_B(0, 1, 0);
    STAGE_B(1, 0, 1); STAGE_A(1, 0, 1);
    asm volatile("s_waitcnt vmcnt(4)" ::: "memory");
    __builtin_amdgcn_s_barrier();

    for (int t = 0; t < nK; ++t) {
        const int d = t & 1, e = d ^ 1;
        const char* ldsA = ldsb + d * 32768 + aoffB;
        const char* ldsBp = ldsb + 65536 + d * 32768 + boffB;
        // ---- P1: quadrant (mh0, nh0) ------------------------------------
        LDA(0); LDB(0);
        if (t + 1 < nK) STAGE_A(e, 1, t + 1);
        __builtin_amdgcn_s_barrier();
        asm volatile("s_waitcnt lgkmcnt(0)" ::: "memory");
        __builtin_amdgcn_sched_barrier(0);
        __builtin_amdgcn_s_setprio(1);
        QUAD(0, 0);
        __builtin_amdgcn_s_setprio(0);
        __builtin_amdgcn_sched_barrier(0);
        __builtin_amdgcn_s_barrier();
        // ---- P2: quadrant (mh0, nh1) ------------------------------------
        LDB(1);
        if (t + 1 < nK) STAGE_B(e, 1, t + 1);
        __builtin_amdgcn_s_barrier();
        asm volatile("s_waitcnt lgkmcnt(0)" ::: "memory");
        __builtin_amdgcn_sched_barrier(0);
        __builtin_amdgcn_s_setprio(1);
        QUAD(0, 1);
        __builtin_amdgcn_s_setprio(0);
        __builtin_amdgcn_sched_barrier(0);
        __builtin_amdgcn_s_barrier();
        // ---- P3: quadrant (mh1, nh1); B reads retired -> stage B0(t+2) ---
        LDA(1);
        if (t + 2 < nK) STAGE_B(d, 0, t + 2);
        __builtin_amdgcn_s_barrier();
        asm volatile("s_waitcnt lgkmcnt(0)" ::: "memory");
        __builtin_amdgcn_sched_barrier(0);
        __builtin_amdgcn_s_setprio(1);
        QUAD(1, 1);
        __builtin_amdgcn_s_setprio(0);
        __builtin_amdgcn_sched_barrier(0);
        __builtin_amdgcn_s_barrier();
        // ---- P4: quadrant (mh1, nh0); A reads retired -> stage A0(t+2) ---
        if (t + 2 < nK) {
            STAGE_A(d, 0, t + 2);
            asm volatile("s_waitcnt vmcnt(4)" ::: "memory"); // tile t+1 landed
        } else {
            asm volatile("s_waitcnt vmcnt(0)" ::: "memory"); // pipeline tail
        }
        __builtin_amdgcn_s_barrier();
        __builtin_amdgcn_s_setprio(1);
        QUAD(1, 0);
        __builtin_amdgcn_s_setprio(0);
        __builtin_amdgcn_sched_barrier(0);
        __builtin_amdgcn_s_barrier();
    }
#undef STAGE_A
#undef STAGE_B
#undef LDA
#undef LDB
#undef QUAD
}

// ---------------- standard-epilogue 256x256 GEMM -----------------------------
__global__ __launch_bounds__(512, 2) void gemm256(const u16* __restrict__ A,
                                                  const u16* __restrict__ Bt,
                                                  void* __restrict__ Cout,
                                                  int M, int N, int K,
                                                  const float* __restrict__ bias,
                                                  const void* __restrict__ resid,
                                                  int relu, int resid_f32, int out_f32) {
    (void)M;
    __shared__ __attribute__((aligned(16))) u16 lds[65536];
    f32x4 acc[8][4] = {};
    const int m0 = blockIdx.y * 256, n0 = blockIdx.x * 256;
    gemm256_core(A, Bt, K, m0, n0, lds, acc);
    const int tid = threadIdx.x;
    const int w = tid >> 6, lane = tid & 63;
    const int quad = lane >> 4, l16 = lane & 15;
    const int wr = w >> 2, wc = w & 3;
#pragma unroll
    for (int nj = 0; nj < 4; ++nj) {
        const int col = n0 + wc * 64 + nj * 16 + l16;
        const float bv = bias ? bias[col] : 0.0f;
#pragma unroll
        for (int mi = 0; mi < 8; ++mi) {
            const int row0 = m0 + wr * 128 + mi * 16 + quad * 4;
#pragma unroll
            for (int r = 0; r < 4; ++r) {
                const size_t idx = (size_t)(row0 + r) * N + col;
                float val = acc[mi][nj][r] + bv;
                if (resid)
                    val += resid_f32 ? ((const float*)resid)[idx]
                                     : b2f(((const u16*)resid)[idx]);
                if (relu) val = fmaxf(val, 0.0f);
                if (out_f32) ((float*)Cout)[idx] = val;
                else         ((u16*)Cout)[idx]   = f2b(val);
            }
        }
    }
}

// ---------------- fused QKV GEMM: [8192 x 3072] = h @ [Wq|Wk|Wv] -------------
// col blocks 0-3 = q, 4-7 = k, 8-11 = v (v written head-transposed for attn).
__global__ __launch_bounds__(512, 2) void gemm256_qkv(const u16* __restrict__ A,
                                                      const u16* __restrict__ Bt,
                                                      u16* __restrict__ qb,
                                                      u16* __restrict__ kb,
                                                      u16* __restrict__ vbT) {
    __shared__ __attribute__((aligned(16))) u16 lds[65536];
    f32x4 acc[8][4] = {};
    const int m0 = blockIdx.y * 256, n0 = blockIdx.x * 256;
    gemm256_core(A, Bt, 1024, m0, n0, lds, acc);
    const int tid = threadIdx.x;
    const int w = tid >> 6, lane = tid & 63;
    const int quad = lane >> 4, l16 = lane & 15;
    const int wr = w >> 2, wc = w & 3;
    const int tens = blockIdx.x >> 2;                 // 0=q, 1=k, 2=v
    const int nbase = (blockIdx.x & 3) * 256 + wc * 64;
    if (tens < 2) {
        u16* dst = tens ? kb : qb;
#pragma unroll
        for (int mi = 0; mi < 8; ++mi) {
            const int row0 = m0 + wr * 128 + mi * 16 + quad * 4;
#pragma unroll
            for (int nj = 0; nj < 4; ++nj) {
                const int colt = nbase + nj * 16 + l16;
#pragma unroll
                for (int r = 0; r < 4; ++r)
                    dst[(size_t)(row0 + r) * 1024 + colt] = f2b(acc[mi][nj][r]);
            }
        }
    } else {
#pragma unroll
        for (int mi = 0; mi < 8; ++mi) {
            const int rowbase = m0 + wr * 128 + mi * 16 + quad * 4;
            const int b = rowbase >> 10, t = rowbase & 1023;
#pragma unroll
            for (int nj = 0; nj < 4; ++nj) {
                const int colt = nbase + nj * 16 + l16;
                const int h = colt >> 6, dd = colt & 63;
                u16x4 tmp;
#pragma unroll
                for (int r = 0; r < 4; ++r) tmp[r] = f2b(acc[mi][nj][r]);
                *(u16x4*)&vbT[(((size_t)(b * 16 + h) * 64 + dd) << 10) + t] = tmp;
            }
        }
    }
}

// ---------------- causal flash attention v3 ----------------------------------
__global__ __launch_bounds__(256) void attn_k(const u16* __restrict__ q,
                                              const u16* __restrict__ k,
                                              const u16* __restrict__ vt,
                                              u16* __restrict__ att) {
    __shared__ __attribute__((aligned(16))) u16 Ks[64][72];
    __shared__ __attribute__((aligned(16))) u16 Vts[64][72];   // [dim][key]
    __shared__ __attribute__((aligned(16))) u16 QP[128 * 72];  // Qs then Ps
    const int qt = 7 - blockIdx.x;
    const int bh = blockIdx.y;
    const int bb = bh >> 4, hd = bh & 15;
    const int q0 = qt * 128;
    const size_t base  = (size_t)bb * 1024 * 1024 + (size_t)hd * 64;
    const size_t vbase = (size_t)bh << 16;
    const int tid = threadIdx.x;
    const int w = tid >> 6, lane = tid & 63;
    const int quad = lane >> 4, l16 = lane & 15;

#pragma unroll
    for (int it = 0; it < 4; ++it) {
        int f = it * 256 + tid;
        int r = f >> 3, c8 = (f & 7) * 8;
        *(u16x8*)&QP[r * 72 + c8] = *(const u16x8*)(q + base + (size_t)(q0 + r) * 1024 + c8);
    }
    __syncthreads();
    bf16x8 qf[2][2];
#pragma unroll
    for (int qi = 0; qi < 2; ++qi)
#pragma unroll
        for (int ks = 0; ks < 2; ++ks)
            qf[qi][ks] = bcast(*(const u16x8*)&QP[(w * 32 + qi * 16 + l16) * 72 + ks * 32 + quad * 8]);
    u16* Ps = &QP[(w * 32) * 72];

    f32x4 oacc[2][4] = {};
    float mrow[2][4], lrow[2][4];
#pragma unroll
    for (int qi = 0; qi < 2; ++qi)
#pragma unroll
        for (int r = 0; r < 4; ++r) { mrow[qi][r] = -1e30f; lrow[qi][r] = 0.0f; }

    const int njt = qt * 2 + 2;
    for (int jt = 0; jt < njt; ++jt) {
        const int j0 = jt * 64;
#pragma unroll
        for (int it = 0; it < 2; ++it) {
            int f = it * 256 + tid;
            int r = f >> 3, c8 = (f & 7) * 8;
            *(u16x8*)&Ks[r][c8]  = *(const u16x8*)(k  + base  + (size_t)(j0 + r) * 1024 + c8);
            *(u16x8*)&Vts[r][c8] = *(const u16x8*)(vt + vbase + (size_t)r * 1024 + j0 + c8);
        }
        __syncthreads();

        // S = Q K^T
        f32x4 s[2][4] = {};
#pragma unroll
        for (int kj = 0; kj < 4; ++kj) {
            bf16x8 b0 = bcast(*(const u16x8*)&Ks[kj * 16 + l16][quad * 8]);
            bf16x8 b1 = bcast(*(const u16x8*)&Ks[kj * 16 + l16][32 + quad * 8]);
#pragma unroll
            for (int qi = 0; qi < 2; ++qi) {
                s[qi][kj] = mfma16(qf[qi][0], b0, s[qi][kj]);
                s[qi][kj] = mfma16(qf[qi][1], b1, s[qi][kj]);
            }
        }

        float tmax[2][4], alpha[2][4], rs[2][4];
#pragma unroll
        for (int qi = 0; qi < 2; ++qi)
#pragma unroll
            for (int r = 0; r < 4; ++r) {
                const int qrow = q0 + w * 32 + qi * 16 + quad * 4 + r;
                float tm = -1e30f;
#pragma unroll
                for (int kj = 0; kj < 4; ++kj) {
                    const int col = j0 + kj * 16 + l16;
                    float sv = s[qi][kj][r] * 0.03125f;
                    sv = (col > qrow) ? -1e30f : sv;
                    s[qi][kj][r] = sv;
                    tm = fmaxf(tm, sv);
                }
                tmax[qi][r] = tm;
            }
#pragma unroll
        for (int qi = 0; qi < 2; ++qi)
#pragma unroll
            for (int r = 0; r < 4; ++r)
                tmax[qi][r] = red_max16(tmax[qi][r]);
#pragma unroll
        for (int qi = 0; qi < 2; ++qi)
#pragma unroll
            for (int r = 0; r < 4; ++r) {
                float mnew = fmaxf(mrow[qi][r], tmax[qi][r]);
                alpha[qi][r] = __expf(mrow[qi][r] - mnew);
                mrow[qi][r] = mnew;
                float accp = 0.0f;
#pragma unroll
                for (int kj = 0; kj < 4; ++kj) {
                    float p = __expf(s[qi][kj][r] - mnew);
                    s[qi][kj][r] = p;
                    accp += p;
                }
                rs[qi][r] = accp;
            }
#pragma unroll
        for (int qi = 0; qi < 2; ++qi)
#pragma unroll
            for (int r = 0; r < 4; ++r)
                rs[qi][r] = red_add16(rs[qi][r]);
#pragma unroll
        for (int qi = 0; qi < 2; ++qi)
#pragma unroll
            for (int r = 0; r < 4; ++r) {
                lrow[qi][r] = lrow[qi][r] * alpha[qi][r] + rs[qi][r];
#pragma unroll
                for (int oj = 0; oj < 4; ++oj) oacc[qi][oj][r] *= alpha[qi][r];
            }
#pragma unroll
        for (int qi = 0; qi < 2; ++qi)
#pragma unroll
            for (int r = 0; r < 4; ++r)
#pragma unroll
                for (int kj = 0; kj < 4; ++kj)
                    Ps[(qi * 16 + quad * 4 + r) * 72 + kj * 16 + l16] = f2b(s[qi][kj][r]);

        // O += P V
#pragma unroll
        for (int ks = 0; ks < 2; ++ks) {
            bf16x8 a0 = bcast(*(const u16x8*)&Ps[(l16) * 72 + ks * 32 + quad * 8]);
            bf16x8 a1 = bcast(*(const u16x8*)&Ps[(16 + l16) * 72 + ks * 32 + quad * 8]);
#pragma unroll
            for (int oj = 0; oj < 4; ++oj) {
                bf16x8 bv = bcast(*(const u16x8*)&Vts[oj * 16 + l16][ks * 32 + quad * 8]);
                oacc[0][oj] = mfma16(a0, bv, oacc[0][oj]);
                oacc[1][oj] = mfma16(a1, bv, oacc[1][oj]);
            }
        }
        __syncthreads();
    }
#pragma unroll
    for (int qi = 0; qi < 2; ++qi)
#pragma unroll
        for (int oj = 0; oj < 4; ++oj)
#pragma unroll
            for (int r = 0; r < 4; ++r) {
                int row = q0 + w * 32 + qi * 16 + quad * 4 + r;
                float o = oacc[qi][oj][r] / lrow[qi][r];
                att[base + (size_t)row * 1024 + oj * 16 + l16] = f2b(o);
            }
}

// ---------------- launch ----------------
extern "C" void kernel_launch(void* const* d_in, const int* in_sizes, int n_in,
                              void* d_out, int out_size, void* d_ws, size_t ws_size,
                              hipStream_t stream) {
    (void)in_sizes; (void)n_in; (void)out_size;
    const float* x   = (const float*)d_in[0];
    const float* Wq  = (const float*)d_in[1];
    const float* Wk  = (const float*)d_in[2];
    const float* Wv  = (const float*)d_in[3];
    const float* Wo  = (const float*)d_in[4];
    const float* bo  = (const float*)d_in[5];
    const float* W1  = (const float*)d_in[6];
    const float* b1  = (const float*)d_in[7];
    const float* W2  = (const float*)d_in[8];
    const float* b2  = (const float*)d_in[9];
    const float* g1  = (const float*)d_in[10];
    const float* be1 = (const float*)d_in[11];
    const float* g2  = (const float*)d_in[12];
    const float* be2 = (const float*)d_in[13];
    float* out = (float*)d_out;

    u16* ws = (u16*)d_ws;
    const size_t MIO = 1024u * 1024u;
    u16* Wt0 = ws;                 // [4 MiO]
    u16* Wt1 = ws + 4 * MIO;       // [4 MiO]
    u16* qb  = ws + 8 * MIO;       // q, later x2 (bf16)
    u16* kb  = ws + 16 * MIO;      // k, later h2 (bf16)
    u16* vb  = ws + 24 * MIO;      // vbT, later FFN hidden (chunked path)
    u16* mid = ws + 32 * MIO;      // [8192][4096] full FFN hidden (if ws allows)
    u16* hb  = (u16*)d_out;        // bf16 scratch: ln1-out, then attn-out
    const int full_ffn = ws_size >= (size_t)64 * MIO * 2;

    dim3 tb32(32, 8);

    ln_k<<<8192, 256, 0, stream>>>(x, g1, be1, hb, 1);

    transpose_k<<<dim3(32, 32), tb32, 0, stream>>>(Wq, Wt0,           1024, 1024);
    transpose_k<<<dim3(32, 32), tb32, 0, stream>>>(Wk, Wt0 + 1 * MIO, 1024, 1024);
    transpose_k<<<dim3(32, 32), tb32, 0, stream>>>(Wv, Wt0 + 2 * MIO, 1024, 1024);
    gemm256_qkv<<<dim3(12, 32), 512, 0, stream>>>(hb, Wt0, qb, kb, vb);

    attn_k<<<dim3(8, 128), 256, 0, stream>>>(qb, kb, vb, hb);

    transpose_k<<<dim3(32, 32), tb32, 0, stream>>>(Wo, Wt1, 1024, 1024);
    gemm256<<<dim3(4, 32), 512, 0, stream>>>(hb, Wt1, qb, 8192, 1024, 1024, bo, x, 0, 1, 0);

    ln_k<<<8192, 256, 0, stream>>>(qb, g2, be2, kb, 0);

    transpose_k<<<dim3(128, 32), tb32, 0, stream>>>(W1, Wt0, 1024, 4096);
    transpose_k<<<dim3(32, 128), tb32, 0, stream>>>(W2, Wt1, 4096, 1024);
    if (full_ffn) {
        gemm256<<<dim3(16, 32), 512, 0, stream>>>(kb, Wt0, mid, 8192, 4096, 1024, b1, nullptr, 1, 0, 0);
        gemm256<<<dim3(4, 32), 512, 0, stream>>>(mid, Wt1, out, 8192, 1024, 4096, b2, qb, 0, 0, 1);
    } else {
        for (int c = 0; c < 4; ++c) {
            const size_t ro = (size_t)c * 2048 * 1024;
            gemm256<<<dim3(16, 8), 512, 0, stream>>>(kb + ro, Wt0, vb, 2048, 4096, 1024, b1, nullptr, 1, 0, 0);
            gemm256<<<dim3(4, 8), 512, 0, stream>>>(vb, Wt1, out + ro, 2048, 1024, 4096, b2, qb + ro, 0, 0, 1);
        }
    }
}

// Round 2
// 609.979 us; speedup vs baseline: 1.0790x; 1.0790x over previous
//
#include <hip/hip_runtime.h>
#include <stdint.h>
#include <stddef.h>

typedef unsigned short u16;
typedef u16 u16x4 __attribute__((ext_vector_type(4)));
typedef u16 u16x8 __attribute__((ext_vector_type(8)));
typedef __bf16 bf16x8 __attribute__((ext_vector_type(8)));
typedef float f32x4 __attribute__((ext_vector_type(4)));

__device__ __forceinline__ float b2f(u16 u) {
    return __uint_as_float(((unsigned)u) << 16);
}
__device__ __forceinline__ u16 f2b(float f) {
    unsigned u = __float_as_uint(f);
    u += 0x7FFF + ((u >> 16) & 1);   // round-to-nearest-even
    return (u16)(u >> 16);
}
__device__ __forceinline__ bf16x8 bcast(u16x8 v) { return __builtin_bit_cast(bf16x8, v); }
__device__ __forceinline__ f32x4 mfma16(bf16x8 a, bf16x8 b, f32x4 c) {
    return __builtin_amdgcn_mfma_f32_16x16x32_bf16(a, b, c, 0, 0, 0);
}
typedef const __attribute__((address_space(1))) void* gas1;
typedef __attribute__((address_space(3))) void* las3;
__device__ __forceinline__ void gload_lds16(const void* g, void* l) {
    __builtin_amdgcn_global_load_lds((gas1)g, (las3)l, 16, 0, 0);
}

// DPP row_ror:N (rotate within 16-lane row) — VALU cross-lane, no LDS.
#define DPP_ROR_F32(x, N) __builtin_bit_cast(float, __builtin_amdgcn_update_dpp( \
    __builtin_bit_cast(int, (x)), __builtin_bit_cast(int, (x)), 0x120 + (N), 0xf, 0xf, false))
__device__ __forceinline__ float red_max16(float x) {
    x = fmaxf(x, DPP_ROR_F32(x, 8));
    x = fmaxf(x, DPP_ROR_F32(x, 4));
    x = fmaxf(x, DPP_ROR_F32(x, 2));
    x = fmaxf(x, DPP_ROR_F32(x, 1));
    return x;
}
__device__ __forceinline__ float red_add16(float x) {
    x += DPP_ROR_F32(x, 8);
    x += DPP_ROR_F32(x, 4);
    x += DPP_ROR_F32(x, 2);
    x += DPP_ROR_F32(x, 1);
    return x;
}

// ---------------- transpose + f32->bf16: out[C][R] = bf16(in[R][C]) ----------
__global__ __launch_bounds__(256) void transpose_k(const float* __restrict__ in,
                                                   u16* __restrict__ out,
                                                   int R, int C) {
    __shared__ u16 t[32][33];
    int x = blockIdx.x * 32 + threadIdx.x;
    int y0 = blockIdx.y * 32;
#pragma unroll
    for (int j = threadIdx.y; j < 32; j += 8)
        t[j][threadIdx.x] = f2b(in[(size_t)(y0 + j) * C + x]);
    __syncthreads();
    int xo = y0 + threadIdx.x;
    int yo0 = blockIdx.x * 32;
#pragma unroll
    for (int j = threadIdx.y; j < 32; j += 8)
        out[(size_t)(yo0 + j) * R + xo] = t[threadIdx.x][j];
}

// ---------------- layernorm over D=1024, one block per row -------------------
__global__ __launch_bounds__(256) void ln_k(const void* __restrict__ x,
                                            const float* __restrict__ g,
                                            const float* __restrict__ b,
                                            u16* __restrict__ y,
                                            int x_f32) {
    const int row = blockIdx.x;
    const size_t ro = (size_t)row * 1024;
    float v[4], s = 0.0f, ss = 0.0f;
#pragma unroll
    for (int i = 0; i < 4; ++i) {
        size_t idx = ro + threadIdx.x + i * 256;
        float f = x_f32 ? ((const float*)x)[idx] : b2f(((const u16*)x)[idx]);
        v[i] = f; s += f; ss += f * f;
    }
#pragma unroll
    for (int off = 32; off; off >>= 1) {
        s += __shfl_down(s, off);
        ss += __shfl_down(ss, off);
    }
    __shared__ float red[2][4];
    int wave = threadIdx.x >> 6, lane = threadIdx.x & 63;
    if (lane == 0) { red[0][wave] = s; red[1][wave] = ss; }
    __syncthreads();
    s = red[0][0] + red[0][1] + red[0][2] + red[0][3];
    ss = red[1][0] + red[1][1] + red[1][2] + red[1][3];
    float mean = s * (1.0f / 1024.0f);
    float var = ss * (1.0f / 1024.0f) - mean * mean;
    float inv = rsqrtf(var + 1e-5f);
#pragma unroll
    for (int i = 0; i < 4; ++i) {
        int c = threadIdx.x + i * 256;
        float o = (v[i] - mean) * inv * g[c] + b[c];
        y[ro + c] = f2b(o);
    }
}

// ---------------- 256x256 8-phase GEMM core (m201-style template) ------------
// NOTE r1: sched_barrier(0) pins REMOVED (m141 trap: they serialized LDS-read
// and MFMA pipes -> 6000 cyc/K-tile vs ~3300 template rate). Compiler now
// interleaves MFMAs across the inline waits (deps are compiler-visible).
__device__ __forceinline__ void gemm256_core(const u16* __restrict__ A,
                                             const u16* __restrict__ Bt,
                                             const int Ksz, const int m0,
                                             const int n0, u16* lds,
                                             f32x4 (&acc)[8][4]) {
    char* ldsb = (char*)lds;
    const int tid = threadIdx.x;
    const int w = tid >> 6, lane = tid & 63;
    const int quad = lane >> 4, l16 = lane & 15;
    const int wr = w >> 2, wc = w & 3;
    const int rS = w * 8 + (lane >> 3);
    const int cS = ((lane & 7) ^ (lane >> 3)) * 8;
    const int dstW = w * 1024;                       // wave-uniform LDS byte off
    const int xo = (l16 & 7) << 4;
    const int co0 = (quad * 16) ^ xo;                // k-step 0
    const int co1 = (64 + quad * 16) ^ xo;           // k-step 1
    const int aoffB = wr * 16384 + l16 * 128;
    const int boffB = (wc >> 1) * 16384 + (wc & 1) * 8192 + l16 * 128;
    const u16* pA = A + (size_t)(m0 + rS) * Ksz + cS;
    const u16* pB = Bt + (size_t)(n0 + rS) * Ksz + cS;
    const int nK = Ksz >> 6;
    const size_t rstep = (size_t)64 * Ksz;

#define STAGE_A(dd, h, kt) do { \
    const u16* _s = pA + (size_t)((h) * 128) * Ksz + (kt) * 64; \
    char* _d = ldsb + (dd) * 32768 + (h) * 16384 + dstW; \
    gload_lds16(_s, _d); \
    gload_lds16(_s + rstep, _d + 8192); \
} while (0)
#define STAGE_B(dd, h, kt) do { \
    const u16* _s = pB + (size_t)((h) * 128) * Ksz + (kt) * 64; \
    char* _d = ldsb + 65536 + (dd) * 32768 + (h) * 16384 + dstW; \
    gload_lds16(_s, _d); \
    gload_lds16(_s + rstep, _d + 8192); \
} while (0)

    bf16x8 af[2][4], bg[2][2][2];

#define LDA(mh) do { \
    _Pragma("unroll") for (int m4 = 0; m4 < 4; ++m4) { \
        af[0][m4] = bcast(*(const u16x8*)(ldsA + ((mh) * 4 + m4) * 2048 + co0)); \
        af[1][m4] = bcast(*(const u16x8*)(ldsA + ((mh) * 4 + m4) * 2048 + co1)); \
    } \
} while (0)
#define LDB(nh) do { \
    _Pragma("unroll") for (int n2 = 0; n2 < 2; ++n2) { \
        bg[(nh)][0][n2] = bcast(*(const u16x8*)(ldsBp + ((nh) * 2 + n2) * 2048 + co0)); \
        bg[(nh)][1][n2] = bcast(*(const u16x8*)(ldsBp + ((nh) * 2 + n2) * 2048 + co1)); \
    } \
} while (0)
#define QUAD(mh, nh) do { \
    _Pragma("unroll") for (int m4 = 0; m4 < 4; ++m4) \
    _Pragma("unroll") for (int n2 = 0; n2 < 2; ++n2) { \
        acc[(mh) * 4 + m4][(nh) * 2 + n2] = \
            mfma16(af[0][m4], bg[(nh)][0][n2], acc[(mh) * 4 + m4][(nh) * 2 + n2]); \
        acc[(mh) * 4 + m4][(nh) * 2 + n2] = \
            mfma16(af[1][m4], bg[(nh)][1][n2], acc[(mh) * 4 + m4][(nh) * 2 + n2]); \
    } \
} while (0)

    // prologue: all 4 halves of tile 0, then B0(1), A0(1)
    STAGE_A(0, 0, 0); STAGE_A(0, 1, 0);
    STAGE_B(0, 0, 0); STAGE_B(0, 1, 0);
    STAGE_B(1, 0, 1); STAGE_A(1, 0, 1);
    asm volatile("s_waitcnt vmcnt(4)" ::: "memory");
    __builtin_amdgcn_s_barrier();

    for (int t = 0; t < nK; ++t) {
        const int d = t & 1, e = d ^ 1;
        const char* ldsA = ldsb + d * 32768 + aoffB;
        const char* ldsBp = ldsb + 65536 + d * 32768 + boffB;
        // ---- P1: quadrant (mh0, nh0) ------------------------------------
        LDA(0); LDB(0);
        if (t + 1 < nK) STAGE_A(e, 1, t + 1);
        __builtin_amdgcn_s_barrier();
        asm volatile("s_waitcnt lgkmcnt(0)" ::: "memory");
        __builtin_amdgcn_s_setprio(1);
        QUAD(0, 0);
        __builtin_amdgcn_s_setprio(0);
        __builtin_amdgcn_s_barrier();
        // ---- P2: quadrant (mh0, nh1) ------------------------------------
        LDB(1);
        if (t + 1 < nK) STAGE_B(e, 1, t + 1);
        __builtin_amdgcn_s_barrier();
        asm volatile("s_waitcnt lgkmcnt(0)" ::: "memory");
        __builtin_amdgcn_s_setprio(1);
        QUAD(0, 1);
        __builtin_amdgcn_s_setprio(0);
        __builtin_amdgcn_s_barrier();
        // ---- P3: quadrant (mh1, nh1); B reads retired -> stage B0(t+2) ---
        LDA(1);
        if (t + 2 < nK) STAGE_B(d, 0, t + 2);
        __builtin_amdgcn_s_barrier();
        asm volatile("s_waitcnt lgkmcnt(0)" ::: "memory");
        __builtin_amdgcn_s_setprio(1);
        QUAD(1, 1);
        __builtin_amdgcn_s_setprio(0);
        __builtin_amdgcn_s_barrier();
        // ---- P4: quadrant (mh1, nh0); A reads retired -> stage A0(t+2) ---
        if (t + 2 < nK) {
            STAGE_A(d, 0, t + 2);
            asm volatile("s_waitcnt vmcnt(4)" ::: "memory"); // tile t+1 landed
        } else {
            asm volatile("s_waitcnt vmcnt(0)" ::: "memory"); // pipeline tail
        }
        __builtin_amdgcn_s_barrier();
        __builtin_amdgcn_s_setprio(1);
        QUAD(1, 0);
        __builtin_amdgcn_s_setprio(0);
        __builtin_amdgcn_s_barrier();
    }
#undef STAGE_A
#undef STAGE_B
#undef LDA
#undef LDB
#undef QUAD
}

// ---------------- 128x256 2-phase GEMM core ----------------------------------
// BM=128, BN=256, BK=64, 512 thr = 8 waves (2Mx4N), wave tile 64x64 = acc[4][4].
// LDS 96 KiB: A dbuf 2x16 KB @0; B dbuf 2x32 KB @32768. Same T2 swizzle.
// 2 phases per K-tile: PA = {LDA(all), LDB(0), stage B1(t+1)} -> QUAD(0);
// PB = {LDB(1), stage A(t+2)+B0(t+2) into just-freed d} -> QUAD(1).
// Counted waits: vmcnt(2) end-PA (A,B0 of t+1 landed), vmcnt(4) end-PB
// (B1 of t+1 landed; A,B0 of t+2 stay in flight). Never drained in-loop.
__device__ __forceinline__ void gemm128_core(const u16* __restrict__ A,
                                             const u16* __restrict__ Bt,
                                             const int Ksz, const int m0,
                                             const int n0, u16* lds,
                                             f32x4 (&acc)[4][4]) {
    char* ldsb = (char*)lds;
    const int tid = threadIdx.x;
    const int w = tid >> 6, lane = tid & 63;
    const int quad = lane >> 4, l16 = lane & 15;
    const int wr = w >> 2, wc = w & 3;
    const int rS = w * 8 + (lane >> 3);
    const int cS = ((lane & 7) ^ (lane >> 3)) * 8;
    const int dstW = w * 1024;
    const int xo = (l16 & 7) << 4;
    const int co0 = (quad * 16) ^ xo;
    const int co1 = (64 + quad * 16) ^ xo;
    const int aoffB = wr * 8192 + l16 * 128;
    const int boffB = wc * 8192 + l16 * 128;
    const u16* pA = A + (size_t)(m0 + rS) * Ksz + cS;
    const u16* pB = Bt + (size_t)(n0 + rS) * Ksz + cS;
    const int nK = Ksz >> 6;
    const size_t rstep = (size_t)64 * Ksz;

#define STG_A(dd, kt) do { \
    const u16* _s = pA + (size_t)(kt) * 64; \
    char* _d = ldsb + (dd) * 16384 + dstW; \
    gload_lds16(_s, _d); \
    gload_lds16(_s + rstep, _d + 8192); \
} while (0)
#define STG_B(dd, h, kt) do { \
    const u16* _s = pB + (size_t)((h) * 128) * Ksz + (kt) * 64; \
    char* _d = ldsb + 32768 + (dd) * 32768 + (h) * 16384 + dstW; \
    gload_lds16(_s, _d); \
    gload_lds16(_s + rstep, _d + 8192); \
} while (0)

    bf16x8 af[2][4], bg[2][2][2];   // af[kk][mi], bg[nh][kk][n2]

#define LDA128() do { \
    _Pragma("unroll") for (int mi = 0; mi < 4; ++mi) { \
        af[0][mi] = bcast(*(const u16x8*)(ldsA + mi * 2048 + co0)); \
        af[1][mi] = bcast(*(const u16x8*)(ldsA + mi * 2048 + co1)); \
    } \
} while (0)
#define LDB128(nh) do { \
    _Pragma("unroll") for (int n2 = 0; n2 < 2; ++n2) { \
        bg[(nh)][0][n2] = bcast(*(const u16x8*)(ldsBp + ((nh) * 2 + n2) * 2048 + co0)); \
        bg[(nh)][1][n2] = bcast(*(const u16x8*)(ldsBp + ((nh) * 2 + n2) * 2048 + co1)); \
    } \
} while (0)
#define QUAD128(nh) do { \
    _Pragma("unroll") for (int mi = 0; mi < 4; ++mi) \
    _Pragma("unroll") for (int n2 = 0; n2 < 2; ++n2) { \
        acc[mi][(nh) * 2 + n2] = mfma16(af[0][mi], bg[(nh)][0][n2], acc[mi][(nh) * 2 + n2]); \
        acc[mi][(nh) * 2 + n2] = mfma16(af[1][mi], bg[(nh)][1][n2], acc[mi][(nh) * 2 + n2]); \
    } \
} while (0)

    // prologue: tile 0 complete (6 loads) + A(1),B0(1) (4 loads)
    STG_A(0, 0); STG_B(0, 0, 0); STG_B(0, 1, 0);
    if (nK > 1) { STG_A(1, 1); STG_B(1, 0, 1); }
    asm volatile("s_waitcnt vmcnt(4)" ::: "memory");
    __builtin_amdgcn_s_barrier();

    for (int t = 0; t < nK; ++t) {
        const int d = t & 1, e = d ^ 1;
        const char* ldsA = ldsb + d * 16384 + aoffB;
        const char* ldsBp = ldsb + 32768 + d * 32768 + boffB;
        // ---- phase A: QUAD(0) -------------------------------------------
        LDA128(); LDB128(0);
        if (t + 1 < nK) STG_B(e, 1, t + 1);
        __builtin_amdgcn_s_barrier();
        asm volatile("s_waitcnt lgkmcnt(0)" ::: "memory");
        __builtin_amdgcn_s_setprio(1);
        QUAD128(0);
        __builtin_amdgcn_s_setprio(0);
        if (t + 1 < nK) asm volatile("s_waitcnt vmcnt(2)" ::: "memory");
        else            asm volatile("s_waitcnt vmcnt(0)" ::: "memory");
        __builtin_amdgcn_s_barrier();
        // ---- phase B: QUAD(1) -------------------------------------------
        LDB128(1);
        if (t + 2 < nK) { STG_A(d, t + 2); STG_B(d, 0, t + 2); }
        __builtin_amdgcn_s_barrier();
        asm volatile("s_waitcnt lgkmcnt(0)" ::: "memory");
        __builtin_amdgcn_s_setprio(1);
        QUAD128(1);
        __builtin_amdgcn_s_setprio(0);
        if (t + 2 < nK) asm volatile("s_waitcnt vmcnt(4)" ::: "memory");
        __builtin_amdgcn_s_barrier();
    }
#undef STG_A
#undef STG_B
#undef LDA128
#undef LDB128
#undef QUAD128
}

// ---------------- standard-epilogue GEMMs ------------------------------------
__global__ __launch_bounds__(512, 2) void gemm256(const u16* __restrict__ A,
                                                  const u16* __restrict__ Bt,
                                                  void* __restrict__ Cout,
                                                  int M, int N, int K,
                                                  const float* __restrict__ bias,
                                                  const void* __restrict__ resid,
                                                  int relu, int resid_f32, int out_f32) {
    (void)M;
    __shared__ __attribute__((aligned(16))) u16 lds[65536];
    f32x4 acc[8][4] = {};
    const int m0 = blockIdx.y * 256, n0 = blockIdx.x * 256;
    gemm256_core(A, Bt, K, m0, n0, lds, acc);
    const int tid = threadIdx.x;
    const int w = tid >> 6, lane = tid & 63;
    const int quad = lane >> 4, l16 = lane & 15;
    const int wr = w >> 2, wc = w & 3;
#pragma unroll
    for (int nj = 0; nj < 4; ++nj) {
        const int col = n0 + wc * 64 + nj * 16 + l16;
        const float bv = bias ? bias[col] : 0.0f;
#pragma unroll
        for (int mi = 0; mi < 8; ++mi) {
            const int row0 = m0 + wr * 128 + mi * 16 + quad * 4;
#pragma unroll
            for (int r = 0; r < 4; ++r) {
                const size_t idx = (size_t)(row0 + r) * N + col;
                float val = acc[mi][nj][r] + bv;
                if (resid)
                    val += resid_f32 ? ((const float*)resid)[idx]
                                     : b2f(((const u16*)resid)[idx]);
                if (relu) val = fmaxf(val, 0.0f);
                if (out_f32) ((float*)Cout)[idx] = val;
                else         ((u16*)Cout)[idx]   = f2b(val);
            }
        }
    }
}

__global__ __launch_bounds__(512, 2) void gemm128(const u16* __restrict__ A,
                                                  const u16* __restrict__ Bt,
                                                  void* __restrict__ Cout,
                                                  int M, int N, int K,
                                                  const float* __restrict__ bias,
                                                  const void* __restrict__ resid,
                                                  int relu, int resid_f32, int out_f32) {
    (void)M;
    __shared__ __attribute__((aligned(16))) u16 lds[49152];
    f32x4 acc[4][4] = {};
    const int m0 = blockIdx.y * 128, n0 = blockIdx.x * 256;
    gemm128_core(A, Bt, K, m0, n0, lds, acc);
    const int tid = threadIdx.x;
    const int w = tid >> 6, lane = tid & 63;
    const int quad = lane >> 4, l16 = lane & 15;
    const int wr = w >> 2, wc = w & 3;
#pragma unroll
    for (int nj = 0; nj < 4; ++nj) {
        const int col = n0 + wc * 64 + nj * 16 + l16;
        const float bv = bias ? bias[col] : 0.0f;
#pragma unroll
        for (int mi = 0; mi < 4; ++mi) {
            const int row0 = m0 + wr * 64 + mi * 16 + quad * 4;
#pragma unroll
            for (int r = 0; r < 4; ++r) {
                const size_t idx = (size_t)(row0 + r) * N + col;
                float val = acc[mi][nj][r] + bv;
                if (resid)
                    val += resid_f32 ? ((const float*)resid)[idx]
                                     : b2f(((const u16*)resid)[idx]);
                if (relu) val = fmaxf(val, 0.0f);
                if (out_f32) ((float*)Cout)[idx] = val;
                else         ((u16*)Cout)[idx]   = f2b(val);
            }
        }
    }
}

// ---------------- fused QKV GEMM (128x256): [8192 x 3072] --------------------
// bx 0-3 = q, 4-7 = k, 8-11 = v (v written head-transposed for attn).
__global__ __launch_bounds__(512, 2) void gemm128_qkv(const u16* __restrict__ A,
                                                      const u16* __restrict__ Bt,
                                                      u16* __restrict__ qb,
                                                      u16* __restrict__ kb,
                                                      u16* __restrict__ vbT) {
    __shared__ __attribute__((aligned(16))) u16 lds[49152];
    f32x4 acc[4][4] = {};
    const int m0 = blockIdx.y * 128, n0 = blockIdx.x * 256;
    gemm128_core(A, Bt, 1024, m0, n0, lds, acc);
    const int tid = threadIdx.x;
    const int w = tid >> 6, lane = tid & 63;
    const int quad = lane >> 4, l16 = lane & 15;
    const int wr = w >> 2, wc = w & 3;
    const int tens = blockIdx.x >> 2;                 // 0=q, 1=k, 2=v
    const int nbase = (blockIdx.x & 3) * 256 + wc * 64;
    if (tens < 2) {
        u16* dst = tens ? kb : qb;
#pragma unroll
        for (int mi = 0; mi < 4; ++mi) {
            const int row0 = m0 + wr * 64 + mi * 16 + quad * 4;
#pragma unroll
            for (int nj = 0; nj < 4; ++nj) {
                const int colt = nbase + nj * 16 + l16;
#pragma unroll
                for (int r = 0; r < 4; ++r)
                    dst[(size_t)(row0 + r) * 1024 + colt] = f2b(acc[mi][nj][r]);
            }
        }
    } else {
#pragma unroll
        for (int mi = 0; mi < 4; ++mi) {
            const int rowbase = m0 + wr * 64 + mi * 16 + quad * 4;
            const int b = rowbase >> 10, t = rowbase & 1023;
#pragma unroll
            for (int nj = 0; nj < 4; ++nj) {
                const int colt = nbase + nj * 16 + l16;
                const int h = colt >> 6, dd = colt & 63;
                u16x4 tmp;
#pragma unroll
                for (int r = 0; r < 4; ++r) tmp[r] = f2b(acc[mi][nj][r]);
                *(u16x4*)&vbT[(((size_t)(b * 16 + h) * 64 + dd) << 10) + t] = tmp;
            }
        }
    }
}

// ---------------- causal flash attention v3 ----------------------------------
__global__ __launch_bounds__(256) void attn_k(const u16* __restrict__ q,
                                              const u16* __restrict__ k,
                                              const u16* __restrict__ vt,
                                              u16* __restrict__ att) {
    __shared__ __attribute__((aligned(16))) u16 Ks[64][72];
    __shared__ __attribute__((aligned(16))) u16 Vts[64][72];   // [dim][key]
    __shared__ __attribute__((aligned(16))) u16 QP[128 * 72];  // Qs then Ps
    const int qt = 7 - blockIdx.x;
    const int bh = blockIdx.y;
    const int bb = bh >> 4, hd = bh & 15;
    const int q0 = qt * 128;
    const size_t base  = (size_t)bb * 1024 * 1024 + (size_t)hd * 64;
    const size_t vbase = (size_t)bh << 16;
    const int tid = threadIdx.x;
    const int w = tid >> 6, lane = tid & 63;
    const int quad = lane >> 4, l16 = lane & 15;

#pragma unroll
    for (int it = 0; it < 4; ++it) {
        int f = it * 256 + tid;
        int r = f >> 3, c8 = (f & 7) * 8;
        *(u16x8*)&QP[r * 72 + c8] = *(const u16x8*)(q + base + (size_t)(q0 + r) * 1024 + c8);
    }
    __syncthreads();
    bf16x8 qf[2][2];
#pragma unroll
    for (int qi = 0; qi < 2; ++qi)
#pragma unroll
        for (int ks = 0; ks < 2; ++ks)
            qf[qi][ks] = bcast(*(const u16x8*)&QP[(w * 32 + qi * 16 + l16) * 72 + ks * 32 + quad * 8]);
    u16* Ps = &QP[(w * 32) * 72];

    f32x4 oacc[2][4] = {};
    float mrow[2][4], lrow[2][4];
#pragma unroll
    for (int qi = 0; qi < 2; ++qi)
#pragma unroll
        for (int r = 0; r < 4; ++r) { mrow[qi][r] = -1e30f; lrow[qi][r] = 0.0f; }

    const int njt = qt * 2 + 2;
    for (int jt = 0; jt < njt; ++jt) {
        const int j0 = jt * 64;
#pragma unroll
        for (int it = 0; it < 2; ++it) {
            int f = it * 256 + tid;
            int r = f >> 3, c8 = (f & 7) * 8;
            *(u16x8*)&Ks[r][c8]  = *(const u16x8*)(k  + base  + (size_t)(j0 + r) * 1024 + c8);
            *(u16x8*)&Vts[r][c8] = *(const u16x8*)(vt + vbase + (size_t)r * 1024 + j0 + c8);
        }
        __syncthreads();

        // S = Q K^T
        f32x4 s[2][4] = {};
#pragma unroll
        for (int kj = 0; kj < 4; ++kj) {
            bf16x8 b0 = bcast(*(const u16x8*)&Ks[kj * 16 + l16][quad * 8]);
            bf16x8 b1 = bcast(*(const u16x8*)&Ks[kj * 16 + l16][32 + quad * 8]);
#pragma unroll
            for (int qi = 0; qi < 2; ++qi) {
                s[qi][kj] = mfma16(qf[qi][0], b0, s[qi][kj]);
                s[qi][kj] = mfma16(qf[qi][1], b1, s[qi][kj]);
            }
        }

        float tmax[2][4], alpha[2][4], rs[2][4];
#pragma unroll
        for (int qi = 0; qi < 2; ++qi)
#pragma unroll
            for (int r = 0; r < 4; ++r) {
                const int qrow = q0 + w * 32 + qi * 16 + quad * 4 + r;
                float tm = -1e30f;
#pragma unroll
                for (int kj = 0; kj < 4; ++kj) {
                    const int col = j0 + kj * 16 + l16;
                    float sv = s[qi][kj][r] * 0.03125f;
                    sv = (col > qrow) ? -1e30f : sv;
                    s[qi][kj][r] = sv;
                    tm = fmaxf(tm, sv);
                }
                tmax[qi][r] = tm;
            }
#pragma unroll
        for (int qi = 0; qi < 2; ++qi)
#pragma unroll
            for (int r = 0; r < 4; ++r)
                tmax[qi][r] = red_max16(tmax[qi][r]);
#pragma unroll
        for (int qi = 0; qi < 2; ++qi)
#pragma unroll
            for (int r = 0; r < 4; ++r) {
                float mnew = fmaxf(mrow[qi][r], tmax[qi][r]);
                alpha[qi][r] = __expf(mrow[qi][r] - mnew);
                mrow[qi][r] = mnew;
                float accp = 0.0f;
#pragma unroll
                for (int kj = 0; kj < 4; ++kj) {
                    float p = __expf(s[qi][kj][r] - mnew);
                    s[qi][kj][r] = p;
                    accp += p;
                }
                rs[qi][r] = accp;
            }
#pragma unroll
        for (int qi = 0; qi < 2; ++qi)
#pragma unroll
            for (int r = 0; r < 4; ++r)
                rs[qi][r] = red_add16(rs[qi][r]);
#pragma unroll
        for (int qi = 0; qi < 2; ++qi)
#pragma unroll
            for (int r = 0; r < 4; ++r) {
                lrow[qi][r] = lrow[qi][r] * alpha[qi][r] + rs[qi][r];
#pragma unroll
                for (int oj = 0; oj < 4; ++oj) oacc[qi][oj][r] *= alpha[qi][r];
            }
#pragma unroll
        for (int qi = 0; qi < 2; ++qi)
#pragma unroll
            for (int r = 0; r < 4; ++r)
#pragma unroll
                for (int kj = 0; kj < 4; ++kj)
                    Ps[(qi * 16 + quad * 4 + r) * 72 + kj * 16 + l16] = f2b(s[qi][kj][r]);

        // O += P V
#pragma unroll
        for (int ks = 0; ks < 2; ++ks) {
            bf16x8 a0 = bcast(*(const u16x8*)&Ps[(l16) * 72 + ks * 32 + quad * 8]);
            bf16x8 a1 = bcast(*(const u16x8*)&Ps[(16 + l16) * 72 + ks * 32 + quad * 8]);
#pragma unroll
            for (int oj = 0; oj < 4; ++oj) {
                bf16x8 bv = bcast(*(const u16x8*)&Vts[oj * 16 + l16][ks * 32 + quad * 8]);
                oacc[0][oj] = mfma16(a0, bv, oacc[0][oj]);
                oacc[1][oj] = mfma16(a1, bv, oacc[1][oj]);
            }
        }
        __syncthreads();
    }
#pragma unroll
    for (int qi = 0; qi < 2; ++qi)
#pragma unroll
        for (int oj = 0; oj < 4; ++oj)
#pragma unroll
            for (int r = 0; r < 4; ++r) {
                int row = q0 + w * 32 + qi * 16 + quad * 4 + r;
                float o = oacc[qi][oj][r] / lrow[qi][r];
                att[base + (size_t)row * 1024 + oj * 16 + l16] = f2b(o);
            }
}

// ---------------- launch ----------------
extern "C" void kernel_launch(void* const* d_in, const int* in_sizes, int n_in,
                              void* d_out, int out_size, void* d_ws, size_t ws_size,
                              hipStream_t stream) {
    (void)in_sizes; (void)n_in; (void)out_size;
    const float* x   = (const float*)d_in[0];
    const float* Wq  = (const float*)d_in[1];
    const float* Wk  = (const float*)d_in[2];
    const float* Wv  = (const float*)d_in[3];
    const float* Wo  = (const float*)d_in[4];
    const float* bo  = (const float*)d_in[5];
    const float* W1  = (const float*)d_in[6];
    const float* b1  = (const float*)d_in[7];
    const float* W2  = (const float*)d_in[8];
    const float* b2  = (const float*)d_in[9];
    const float* g1  = (const float*)d_in[10];
    const float* be1 = (const float*)d_in[11];
    const float* g2  = (const float*)d_in[12];
    const float* be2 = (const float*)d_in[13];
    float* out = (float*)d_out;

    u16* ws = (u16*)d_ws;
    const size_t MIO = 1024u * 1024u;
    u16* Wt0 = ws;                 // [4 MiO]
    u16* Wt1 = ws + 4 * MIO;       // [4 MiO]
    u16* qb  = ws + 8 * MIO;       // q, later x2 (bf16)
    u16* kb  = ws + 16 * MIO;      // k, later h2 (bf16)
    u16* vb  = ws + 24 * MIO;      // vbT, later FFN hidden (chunked path)
    u16* mid = ws + 32 * MIO;      // [8192][4096] full FFN hidden (if ws allows)
    u16* hb  = (u16*)d_out;        // bf16 scratch: ln1-out, then attn-out
    const int full_ffn = ws_size >= (size_t)64 * MIO * 2;

    dim3 tb32(32, 8);

    ln_k<<<8192, 256, 0, stream>>>(x, g1, be1, hb, 1);

    transpose_k<<<dim3(32, 32), tb32, 0, stream>>>(Wq, Wt0,           1024, 1024);
    transpose_k<<<dim3(32, 32), tb32, 0, stream>>>(Wk, Wt0 + 1 * MIO, 1024, 1024);
    transpose_k<<<dim3(32, 32), tb32, 0, stream>>>(Wv, Wt0 + 2 * MIO, 1024, 1024);
    gemm128_qkv<<<dim3(12, 64), 512, 0, stream>>>(hb, Wt0, qb, kb, vb);

    attn_k<<<dim3(8, 128), 256, 0, stream>>>(qb, kb, vb, hb);

    transpose_k<<<dim3(32, 32), tb32, 0, stream>>>(Wo, Wt1, 1024, 1024);
    gemm128<<<dim3(4, 64), 512, 0, stream>>>(hb, Wt1, qb, 8192, 1024, 1024, bo, x, 0, 1, 0);

    ln_k<<<8192, 256, 0, stream>>>(qb, g2, be2, kb, 0);

    transpose_k<<<dim3(128, 32), tb32, 0, stream>>>(W1, Wt0, 1024, 4096);
    transpose_k<<<dim3(32, 128), tb32, 0, stream>>>(W2, Wt1, 4096, 1024);
    if (full_ffn) {
        gemm256<<<dim3(16, 32), 512, 0, stream>>>(kb, Wt0, mid, 8192, 4096, 1024, b1, nullptr, 1, 0, 0);
        gemm128<<<dim3(4, 64), 512, 0, stream>>>(mid, Wt1, out, 8192, 1024, 4096, b2, qb, 0, 0, 1);
    } else {
        for (int c = 0; c < 4; ++c) {
            const size_t ro = (size_t)c * 2048 * 1024;
            gemm128<<<dim3(16, 16), 512, 0, stream>>>(kb + ro, Wt0, vb, 2048, 4096, 1024, b1, nullptr, 1, 0, 0);
            gemm128<<<dim3(4, 16), 512, 0, stream>>>(vb, Wt1, out + ro, 2048, 1024, 4096, b2, qb + ro, 0, 0, 1);
        }
    }
}

// Round 4
// 562.936 us; speedup vs baseline: 1.1692x; 1.0836x over previous
//
#include <hip/hip_runtime.h>
#include <stdint.h>
#include <stddef.h>

typedef unsigned short u16;
typedef u16 u16x4 __attribute__((ext_vector_type(4)));
typedef u16 u16x8 __attribute__((ext_vector_type(8)));
typedef __bf16 bf16x8 __attribute__((ext_vector_type(8)));
typedef float f32x4 __attribute__((ext_vector_type(4)));

__device__ __forceinline__ float b2f(u16 u) {
    return __uint_as_float(((unsigned)u) << 16);
}
__device__ __forceinline__ u16 f2b(float f) {
    unsigned u = __float_as_uint(f);
    u += 0x7FFF + ((u >> 16) & 1);   // round-to-nearest-even
    return (u16)(u >> 16);
}
__device__ __forceinline__ bf16x8 bcast(u16x8 v) { return __builtin_bit_cast(bf16x8, v); }
__device__ __forceinline__ f32x4 mfma16(bf16x8 a, bf16x8 b, f32x4 c) {
    return __builtin_amdgcn_mfma_f32_16x16x32_bf16(a, b, c, 0, 0, 0);
}
typedef const __attribute__((address_space(1))) void* gas1;
typedef __attribute__((address_space(3))) void* las3;
__device__ __forceinline__ void gload_lds16(const void* g, void* l) {
    __builtin_amdgcn_global_load_lds((gas1)g, (las3)l, 16, 0, 0);
}

// DPP row_ror:N (rotate within 16-lane row) — VALU cross-lane, no LDS.
#define DPP_ROR_F32(x, N) __builtin_bit_cast(float, __builtin_amdgcn_update_dpp( \
    __builtin_bit_cast(int, (x)), __builtin_bit_cast(int, (x)), 0x120 + (N), 0xf, 0xf, false))
__device__ __forceinline__ float red_max16(float x) {
    x = fmaxf(x, DPP_ROR_F32(x, 8));
    x = fmaxf(x, DPP_ROR_F32(x, 4));
    x = fmaxf(x, DPP_ROR_F32(x, 2));
    x = fmaxf(x, DPP_ROR_F32(x, 1));
    return x;
}
__device__ __forceinline__ float red_add16(float x) {
    x += DPP_ROR_F32(x, 8);
    x += DPP_ROR_F32(x, 4);
    x += DPP_ROR_F32(x, 2);
    x += DPP_ROR_F32(x, 1);
    return x;
}

// ---------------- transpose + f32->bf16: out[C][R] = bf16(in[R][C]) ----------
__global__ __launch_bounds__(256) void transpose_k(const float* __restrict__ in,
                                                   u16* __restrict__ out,
                                                   int R, int C) {
    __shared__ u16 t[32][33];
    int x = blockIdx.x * 32 + threadIdx.x;
    int y0 = blockIdx.y * 32;
#pragma unroll
    for (int j = threadIdx.y; j < 32; j += 8)
        t[j][threadIdx.x] = f2b(in[(size_t)(y0 + j) * C + x]);
    __syncthreads();
    int xo = y0 + threadIdx.x;
    int yo0 = blockIdx.x * 32;
#pragma unroll
    for (int j = threadIdx.y; j < 32; j += 8)
        out[(size_t)(yo0 + j) * R + xo] = t[threadIdx.x][j];
}

// ---------------- layernorm over D=1024, one block per row -------------------
__global__ __launch_bounds__(256) void ln_k(const void* __restrict__ x,
                                            const float* __restrict__ g,
                                            const float* __restrict__ b,
                                            u16* __restrict__ y,
                                            int x_f32) {
    const int row = blockIdx.x;
    const size_t ro = (size_t)row * 1024;
    float v[4], s = 0.0f, ss = 0.0f;
#pragma unroll
    for (int i = 0; i < 4; ++i) {
        size_t idx = ro + threadIdx.x + i * 256;
        float f = x_f32 ? ((const float*)x)[idx] : b2f(((const u16*)x)[idx]);
        v[i] = f; s += f; ss += f * f;
    }
#pragma unroll
    for (int off = 32; off; off >>= 1) {
        s += __shfl_down(s, off);
        ss += __shfl_down(ss, off);
    }
    __shared__ float red[2][4];
    int wave = threadIdx.x >> 6, lane = threadIdx.x & 63;
    if (lane == 0) { red[0][wave] = s; red[1][wave] = ss; }
    __syncthreads();
    s = red[0][0] + red[0][1] + red[0][2] + red[0][3];
    ss = red[1][0] + red[1][1] + red[1][2] + red[1][3];
    float mean = s * (1.0f / 1024.0f);
    float var = ss * (1.0f / 1024.0f) - mean * mean;
    float inv = rsqrtf(var + 1e-5f);
#pragma unroll
    for (int i = 0; i < 4; ++i) {
        int c = threadIdx.x + i * 256;
        float o = (v[i] - mean) * inv * g[c] + b[c];
        y[ro + c] = f2b(o);
    }
}

// ---------------- 128x256 GEMM core (race-free schedule, r4) -----------------
// BM=128, BN=256, BK=64, 512 thr = 8 waves (2Mx4N), wave tile 64x64 = acc[4][4].
// LDS 96 KiB: A dbuf 2x16 KB @0; B dbuf 2x32 KB @32768. T2 swizzle via
// inverse-swizzled global source (linear gload_lds dest) + swizzled ds_read.
//
// RACE POST-MORTEM (r3 fail): staging tile t+2 into the buffer CURRENTLY being
// consumed is unsafe — each wave's 64 B-rows live in ONE half, so B half 0 is
// read in BOTH phases; STG_B(d,0,t+2) in phase B raced other waves' pending
// LDB128(1) reads. With 2 buffers, t+1 may only go into nxt (fully retired at
// the previous iteration-end barrier).
// SAFE schedule: issue ALL 6 loads of tile t+1 at the TOP of iteration t;
// consume tile t (~1500 LDS-pipe cyc) in between; vmcnt(0) only at iteration
// end — issue-to-wait distance >= HBM latency, so the drain is free.
// ONE barrier per K-tile (no intra-iteration cross-wave hazard remains).
__device__ __forceinline__ void gemm128_core(const u16* __restrict__ A,
                                             const u16* __restrict__ Bt,
                                             const int Ksz, const int m0,
                                             const int n0, u16* lds,
                                             f32x4 (&acc)[4][4]) {
    char* ldsb = (char*)lds;
    const int tid = threadIdx.x;
    const int w = tid >> 6, lane = tid & 63;
    const int quad = lane >> 4, l16 = lane & 15;
    const int wr = w >> 2, wc = w & 3;
    const int rS = w * 8 + (lane >> 3);
    const int cS = ((lane & 7) ^ (lane >> 3)) * 8;
    const int dstW = w * 1024;
    const int xo = (l16 & 7) << 4;
    const int co0 = (quad * 16) ^ xo;
    const int co1 = (64 + quad * 16) ^ xo;
    const int aoffB = wr * 8192 + l16 * 128;
    const int boffB = wc * 8192 + l16 * 128;
    const u16* pA = A + (size_t)(m0 + rS) * Ksz + cS;
    const u16* pB = Bt + (size_t)(n0 + rS) * Ksz + cS;
    const int nK = Ksz >> 6;
    const size_t rstep = (size_t)64 * Ksz;

#define STG_A(dd, kt) do { \
    const u16* _s = pA + (size_t)(kt) * 64; \
    char* _d = ldsb + (dd) * 16384 + dstW; \
    gload_lds16(_s, _d); \
    gload_lds16(_s + rstep, _d + 8192); \
} while (0)
#define STG_B(dd, h, kt) do { \
    const u16* _s = pB + (size_t)((h) * 128) * Ksz + (kt) * 64; \
    char* _d = ldsb + 32768 + (dd) * 32768 + (h) * 16384 + dstW; \
    gload_lds16(_s, _d); \
    gload_lds16(_s + rstep, _d + 8192); \
} while (0)

    bf16x8 af[2][4], bg[2][2][2];   // af[kk][mi], bg[nh][kk][n2]

#define LDA128() do { \
    _Pragma("unroll") for (int mi = 0; mi < 4; ++mi) { \
        af[0][mi] = bcast(*(const u16x8*)(ldsA + mi * 2048 + co0)); \
        af[1][mi] = bcast(*(const u16x8*)(ldsA + mi * 2048 + co1)); \
    } \
} while (0)
#define LDB128(nh) do { \
    _Pragma("unroll") for (int n2 = 0; n2 < 2; ++n2) { \
        bg[(nh)][0][n2] = bcast(*(const u16x8*)(ldsBp + ((nh) * 2 + n2) * 2048 + co0)); \
        bg[(nh)][1][n2] = bcast(*(const u16x8*)(ldsBp + ((nh) * 2 + n2) * 2048 + co1)); \
    } \
} while (0)
#define QUAD128(nh) do { \
    _Pragma("unroll") for (int mi = 0; mi < 4; ++mi) \
    _Pragma("unroll") for (int n2 = 0; n2 < 2; ++n2) { \
        acc[mi][(nh) * 2 + n2] = mfma16(af[0][mi], bg[(nh)][0][n2], acc[mi][(nh) * 2 + n2]); \
        acc[mi][(nh) * 2 + n2] = mfma16(af[1][mi], bg[(nh)][1][n2], acc[mi][(nh) * 2 + n2]); \
    } \
} while (0)

    // prologue: tile 0 (6 loads), drain, publish
    STG_A(0, 0); STG_B(0, 0, 0); STG_B(0, 1, 0);
    asm volatile("s_waitcnt vmcnt(0)" ::: "memory");
    __builtin_amdgcn_s_barrier();
    asm volatile("" ::: "memory");      // keep later ops below the barrier

    for (int t = 0; t < nK; ++t) {
        const int d = t & 1, e = d ^ 1;
        const char* ldsA = ldsb + d * 16384 + aoffB;
        const char* ldsBp = ldsb + 32768 + d * 32768 + boffB;
        // issue ALL of tile t+1 into nxt (fully retired since last barrier)
        if (t + 1 < nK) { STG_A(e, t + 1); STG_B(e, 0, t + 1); STG_B(e, 1, t + 1); }
        // phase A
        LDA128(); LDB128(0);
        asm volatile("s_waitcnt lgkmcnt(0)" ::: "memory");
        __builtin_amdgcn_s_setprio(1);
        QUAD128(0);
        __builtin_amdgcn_s_setprio(0);
        // phase B
        LDB128(1);
        asm volatile("s_waitcnt lgkmcnt(0)" ::: "memory");
        __builtin_amdgcn_s_setprio(1);
        QUAD128(1);
        __builtin_amdgcn_s_setprio(0);
        // tile t+1 landed (issued ~1 iteration ago -> usually zero stall)
        asm volatile("s_waitcnt vmcnt(0)" ::: "memory");
        __builtin_amdgcn_s_barrier();
        asm volatile("" ::: "memory");
    }
#undef STG_A
#undef STG_B
#undef LDA128
#undef LDB128
#undef QUAD128
}

// ---------------- gemm128 with fused epilogue --------------------------------
// bf16 outputs: per-wave LDS repack (64x72 u16 patch, private -> no barrier)
// then full-128B-line streaming stores (kills 2.4x write amplification).
// f32 outputs: direct scatter (64B runs, measured non-amplifying).
__global__ __launch_bounds__(512, 2) void gemm128(const u16* __restrict__ A,
                                                  const u16* __restrict__ Bt,
                                                  void* __restrict__ Cout,
                                                  int M, int N, int K,
                                                  const float* __restrict__ bias,
                                                  const void* __restrict__ resid,
                                                  int relu, int resid_f32, int out_f32) {
    (void)M;
    __shared__ __attribute__((aligned(16))) u16 lds[49152];
    f32x4 acc[4][4] = {};
    const int m0 = blockIdx.y * 128, n0 = blockIdx.x * 256;
    gemm128_core(A, Bt, K, m0, n0, lds, acc);
    const int tid = threadIdx.x;
    const int w = tid >> 6, lane = tid & 63;
    const int quad = lane >> 4, l16 = lane & 15;
    const int wr = w >> 2, wc = w & 3;
    const int row0 = m0 + wr * 64;
    if (out_f32) {
#pragma unroll
        for (int nj = 0; nj < 4; ++nj) {
            const int col = n0 + wc * 64 + nj * 16 + l16;
            const float bv = bias ? bias[col] : 0.0f;
#pragma unroll
            for (int mi = 0; mi < 4; ++mi) {
#pragma unroll
                for (int r = 0; r < 4; ++r) {
                    const size_t idx = (size_t)(row0 + mi * 16 + quad * 4 + r) * N + col;
                    float val = acc[mi][nj][r] + bv;
                    if (resid)
                        val += resid_f32 ? ((const float*)resid)[idx]
                                         : b2f(((const u16*)resid)[idx]);
                    if (relu) val = fmaxf(val, 0.0f);
                    ((float*)Cout)[idx] = val;
                }
            }
        }
    } else {
        u16* patch = &lds[w * 4608];       // 64 rows x 72 u16 (144B stride)
#pragma unroll
        for (int nj = 0; nj < 4; ++nj) {
            const int col = n0 + wc * 64 + nj * 16 + l16;
            const float bv = bias ? bias[col] : 0.0f;
#pragma unroll
            for (int mi = 0; mi < 4; ++mi) {
#pragma unroll
                for (int r = 0; r < 4; ++r) {
                    const int lr = mi * 16 + quad * 4 + r;
                    float val = acc[mi][nj][r] + bv;
                    if (resid) {
                        const size_t idx = (size_t)(row0 + lr) * N + col;
                        val += resid_f32 ? ((const float*)resid)[idx]
                                         : b2f(((const u16*)resid)[idx]);
                    }
                    if (relu) val = fmaxf(val, 0.0f);
                    patch[lr * 72 + nj * 16 + l16] = f2b(val);
                }
            }
        }
        asm volatile("s_waitcnt lgkmcnt(0)" ::: "memory");
        const int pr = lane >> 3, pc = (lane & 7) * 8;
        u16* gout = (u16*)Cout + (size_t)row0 * N + n0 + wc * 64;
#pragma unroll
        for (int p = 0; p < 8; ++p) {
            u16x8 v = *(const u16x8*)&patch[(p * 8 + pr) * 72 + pc];
            *(u16x8*)&gout[(size_t)(p * 8 + pr) * N + pc] = v;
        }
    }
}

// ---------------- fused QKV GEMM (128x256): [8192 x 3072] --------------------
// bx 0-3 = q, 4-7 = k, 8-11 = v (v written head-transposed [B*H][64][1024]).
// All outputs via per-wave LDS repack -> full-line stores (vT scatter was 16x
// write-amplified: 8B runs at 2KB stride).
__global__ __launch_bounds__(512, 2) void gemm128_qkv(const u16* __restrict__ A,
                                                      const u16* __restrict__ Bt,
                                                      u16* __restrict__ qb,
                                                      u16* __restrict__ kb,
                                                      u16* __restrict__ vbT) {
    __shared__ __attribute__((aligned(16))) u16 lds[49152];
    f32x4 acc[4][4] = {};
    const int m0 = blockIdx.y * 128, n0 = blockIdx.x * 256;
    gemm128_core(A, Bt, 1024, m0, n0, lds, acc);
    const int tid = threadIdx.x;
    const int w = tid >> 6, lane = tid & 63;
    const int quad = lane >> 4, l16 = lane & 15;
    const int wr = w >> 2, wc = w & 3;
    const int row0 = m0 + wr * 64;
    const int tens = blockIdx.x >> 2;                 // 0=q, 1=k, 2=v
    const int nbase = (blockIdx.x & 3) * 256 + wc * 64;
    u16* patch = &lds[w * 4608];                      // 64 x 72 u16
    const int pr = lane >> 3, pc = (lane & 7) * 8;
    if (tens < 2) {
        u16* dst = tens ? kb : qb;
#pragma unroll
        for (int mi = 0; mi < 4; ++mi)
#pragma unroll
            for (int nj = 0; nj < 4; ++nj)
#pragma unroll
                for (int r = 0; r < 4; ++r)
                    patch[(mi * 16 + quad * 4 + r) * 72 + nj * 16 + l16] =
                        f2b(acc[mi][nj][r]);
        asm volatile("s_waitcnt lgkmcnt(0)" ::: "memory");
        u16* gout = dst + (size_t)row0 * 1024 + nbase;
#pragma unroll
        for (int p = 0; p < 8; ++p) {
            u16x8 v = *(const u16x8*)&patch[(p * 8 + pr) * 72 + pc];
            *(u16x8*)&gout[(size_t)(p * 8 + pr) * 1024 + pc] = v;
        }
    } else {
        // patch holds [d 0..63][t 0..63]: d = nj*16+l16, t = mi*16+quad*4+r
#pragma unroll
        for (int mi = 0; mi < 4; ++mi)
#pragma unroll
            for (int nj = 0; nj < 4; ++nj)
#pragma unroll
                for (int r = 0; r < 4; ++r)
                    patch[(nj * 16 + l16) * 72 + mi * 16 + quad * 4 + r] =
                        f2b(acc[mi][nj][r]);
        asm volatile("s_waitcnt lgkmcnt(0)" ::: "memory");
        const int b = row0 >> 10, t0 = row0 & 1023;
        const int h = nbase >> 6;                     // head index 0..15
        u16* gout = vbT + (((size_t)(b * 16 + h) * 64) << 10) + t0;
#pragma unroll
        for (int p = 0; p < 8; ++p) {
            u16x8 v = *(const u16x8*)&patch[(p * 8 + pr) * 72 + pc];
            *(u16x8*)&gout[((size_t)(p * 8 + pr) << 10) + pc] = v;
        }
    }
}

// ---------------- causal flash attention v3 ----------------------------------
__global__ __launch_bounds__(256) void attn_k(const u16* __restrict__ q,
                                              const u16* __restrict__ k,
                                              const u16* __restrict__ vt,
                                              u16* __restrict__ att) {
    __shared__ __attribute__((aligned(16))) u16 Ks[64][72];
    __shared__ __attribute__((aligned(16))) u16 Vts[64][72];   // [dim][key]
    __shared__ __attribute__((aligned(16))) u16 QP[128 * 72];  // Qs then Ps
    const int qt = 7 - blockIdx.x;
    const int bh = blockIdx.y;
    const int bb = bh >> 4, hd = bh & 15;
    const int q0 = qt * 128;
    const size_t base  = (size_t)bb * 1024 * 1024 + (size_t)hd * 64;
    const size_t vbase = (size_t)bh << 16;
    const int tid = threadIdx.x;
    const int w = tid >> 6, lane = tid & 63;
    const int quad = lane >> 4, l16 = lane & 15;

#pragma unroll
    for (int it = 0; it < 4; ++it) {
        int f = it * 256 + tid;
        int r = f >> 3, c8 = (f & 7) * 8;
        *(u16x8*)&QP[r * 72 + c8] = *(const u16x8*)(q + base + (size_t)(q0 + r) * 1024 + c8);
    }
    __syncthreads();
    bf16x8 qf[2][2];
#pragma unroll
    for (int qi = 0; qi < 2; ++qi)
#pragma unroll
        for (int ks = 0; ks < 2; ++ks)
            qf[qi][ks] = bcast(*(const u16x8*)&QP[(w * 32 + qi * 16 + l16) * 72 + ks * 32 + quad * 8]);
    u16* Ps = &QP[(w * 32) * 72];

    f32x4 oacc[2][4] = {};
    float mrow[2][4], lrow[2][4];
#pragma unroll
    for (int qi = 0; qi < 2; ++qi)
#pragma unroll
        for (int r = 0; r < 4; ++r) { mrow[qi][r] = -1e30f; lrow[qi][r] = 0.0f; }

    const int njt = qt * 2 + 2;
    for (int jt = 0; jt < njt; ++jt) {
        const int j0 = jt * 64;
#pragma unroll
        for (int it = 0; it < 2; ++it) {
            int f = it * 256 + tid;
            int r = f >> 3, c8 = (f & 7) * 8;
            *(u16x8*)&Ks[r][c8]  = *(const u16x8*)(k  + base  + (size_t)(j0 + r) * 1024 + c8);
            *(u16x8*)&Vts[r][c8] = *(const u16x8*)(vt + vbase + (size_t)r * 1024 + j0 + c8);
        }
        __syncthreads();

        // S = Q K^T
        f32x4 s[2][4] = {};
#pragma unroll
        for (int kj = 0; kj < 4; ++kj) {
            bf16x8 b0 = bcast(*(const u16x8*)&Ks[kj * 16 + l16][quad * 8]);
            bf16x8 b1 = bcast(*(const u16x8*)&Ks[kj * 16 + l16][32 + quad * 8]);
#pragma unroll
            for (int qi = 0; qi < 2; ++qi) {
                s[qi][kj] = mfma16(qf[qi][0], b0, s[qi][kj]);
                s[qi][kj] = mfma16(qf[qi][1], b1, s[qi][kj]);
            }
        }

        float tmax[2][4], alpha[2][4], rs[2][4];
#pragma unroll
        for (int qi = 0; qi < 2; ++qi)
#pragma unroll
            for (int r = 0; r < 4; ++r) {
                const int qrow = q0 + w * 32 + qi * 16 + quad * 4 + r;
                float tm = -1e30f;
#pragma unroll
                for (int kj = 0; kj < 4; ++kj) {
                    const int col = j0 + kj * 16 + l16;
                    float sv = s[qi][kj][r] * 0.03125f;
                    sv = (col > qrow) ? -1e30f : sv;
                    s[qi][kj][r] = sv;
                    tm = fmaxf(tm, sv);
                }
                tmax[qi][r] = tm;
            }
#pragma unroll
        for (int qi = 0; qi < 2; ++qi)
#pragma unroll
            for (int r = 0; r < 4; ++r)
                tmax[qi][r] = red_max16(tmax[qi][r]);
#pragma unroll
        for (int qi = 0; qi < 2; ++qi)
#pragma unroll
            for (int r = 0; r < 4; ++r) {
                float mnew = fmaxf(mrow[qi][r], tmax[qi][r]);
                alpha[qi][r] = __expf(mrow[qi][r] - mnew);
                mrow[qi][r] = mnew;
                float accp = 0.0f;
#pragma unroll
                for (int kj = 0; kj < 4; ++kj) {
                    float p = __expf(s[qi][kj][r] - mnew);
                    s[qi][kj][r] = p;
                    accp += p;
                }
                rs[qi][r] = accp;
            }
#pragma unroll
        for (int qi = 0; qi < 2; ++qi)
#pragma unroll
            for (int r = 0; r < 4; ++r)
                rs[qi][r] = red_add16(rs[qi][r]);
#pragma unroll
        for (int qi = 0; qi < 2; ++qi)
#pragma unroll
            for (int r = 0; r < 4; ++r) {
                lrow[qi][r] = lrow[qi][r] * alpha[qi][r] + rs[qi][r];
#pragma unroll
                for (int oj = 0; oj < 4; ++oj) oacc[qi][oj][r] *= alpha[qi][r];
            }
#pragma unroll
        for (int qi = 0; qi < 2; ++qi)
#pragma unroll
            for (int r = 0; r < 4; ++r)
#pragma unroll
                for (int kj = 0; kj < 4; ++kj)
                    Ps[(qi * 16 + quad * 4 + r) * 72 + kj * 16 + l16] = f2b(s[qi][kj][r]);

        // O += P V
#pragma unroll
        for (int ks = 0; ks < 2; ++ks) {
            bf16x8 a0 = bcast(*(const u16x8*)&Ps[(l16) * 72 + ks * 32 + quad * 8]);
            bf16x8 a1 = bcast(*(const u16x8*)&Ps[(16 + l16) * 72 + ks * 32 + quad * 8]);
#pragma unroll
            for (int oj = 0; oj < 4; ++oj) {
                bf16x8 bv = bcast(*(const u16x8*)&Vts[oj * 16 + l16][ks * 32 + quad * 8]);
                oacc[0][oj] = mfma16(a0, bv, oacc[0][oj]);
                oacc[1][oj] = mfma16(a1, bv, oacc[1][oj]);
            }
        }
        __syncthreads();
    }
#pragma unroll
    for (int qi = 0; qi < 2; ++qi)
#pragma unroll
        for (int oj = 0; oj < 4; ++oj)
#pragma unroll
            for (int r = 0; r < 4; ++r) {
                int row = q0 + w * 32 + qi * 16 + quad * 4 + r;
                float o = oacc[qi][oj][r] / lrow[qi][r];
                att[base + (size_t)row * 1024 + oj * 16 + l16] = f2b(o);
            }
}

// ---------------- launch ----------------
extern "C" void kernel_launch(void* const* d_in, const int* in_sizes, int n_in,
                              void* d_out, int out_size, void* d_ws, size_t ws_size,
                              hipStream_t stream) {
    (void)in_sizes; (void)n_in; (void)out_size;
    const float* x   = (const float*)d_in[0];
    const float* Wq  = (const float*)d_in[1];
    const float* Wk  = (const float*)d_in[2];
    const float* Wv  = (const float*)d_in[3];
    const float* Wo  = (const float*)d_in[4];
    const float* bo  = (const float*)d_in[5];
    const float* W1  = (const float*)d_in[6];
    const float* b1  = (const float*)d_in[7];
    const float* W2  = (const float*)d_in[8];
    const float* b2  = (const float*)d_in[9];
    const float* g1  = (const float*)d_in[10];
    const float* be1 = (const float*)d_in[11];
    const float* g2  = (const float*)d_in[12];
    const float* be2 = (const float*)d_in[13];
    float* out = (float*)d_out;

    u16* ws = (u16*)d_ws;
    const size_t MIO = 1024u * 1024u;
    u16* Wt0 = ws;                 // [4 MiO]
    u16* Wt1 = ws + 4 * MIO;       // [4 MiO]
    u16* qb  = ws + 8 * MIO;       // q, later x2 (bf16)
    u16* kb  = ws + 16 * MIO;      // k, later h2 (bf16)
    u16* vb  = ws + 24 * MIO;      // vbT, later FFN hidden (chunked path)
    u16* mid = ws + 32 * MIO;      // [8192][4096] full FFN hidden (if ws allows)
    u16* hb  = (u16*)d_out;        // bf16 scratch: ln1-out, then attn-out
    const int full_ffn = ws_size >= (size_t)64 * MIO * 2;

    dim3 tb32(32, 8);

    ln_k<<<8192, 256, 0, stream>>>(x, g1, be1, hb, 1);

    transpose_k<<<dim3(32, 32), tb32, 0, stream>>>(Wq, Wt0,           1024, 1024);
    transpose_k<<<dim3(32, 32), tb32, 0, stream>>>(Wk, Wt0 + 1 * MIO, 1024, 1024);
    transpose_k<<<dim3(32, 32), tb32, 0, stream>>>(Wv, Wt0 + 2 * MIO, 1024, 1024);
    gemm128_qkv<<<dim3(12, 64), 512, 0, stream>>>(hb, Wt0, qb, kb, vb);

    attn_k<<<dim3(8, 128), 256, 0, stream>>>(qb, kb, vb, hb);

    transpose_k<<<dim3(32, 32), tb32, 0, stream>>>(Wo, Wt1, 1024, 1024);
    gemm128<<<dim3(4, 64), 512, 0, stream>>>(hb, Wt1, qb, 8192, 1024, 1024, bo, x, 0, 1, 0);

    ln_k<<<8192, 256, 0, stream>>>(qb, g2, be2, kb, 0);

    transpose_k<<<dim3(128, 32), tb32, 0, stream>>>(W1, Wt0, 1024, 4096);
    transpose_k<<<dim3(32, 128), tb32, 0, stream>>>(W2, Wt1, 4096, 1024);
    if (full_ffn) {
        gemm128<<<dim3(16, 64), 512, 0, stream>>>(kb, Wt0, mid, 8192, 4096, 1024, b1, nullptr, 1, 0, 0);
        gemm128<<<dim3(4, 64), 512, 0, stream>>>(mid, Wt1, out, 8192, 1024, 4096, b2, qb, 0, 0, 1);
    } else {
        for (int c = 0; c < 4; ++c) {
            const size_t ro = (size_t)c * 2048 * 1024;
            gemm128<<<dim3(16, 16), 512, 0, stream>>>(kb + ro, Wt0, vb, 2048, 4096, 1024, b1, nullptr, 1, 0, 0);
            gemm128<<<dim3(4, 16), 512, 0, stream>>>(vb, Wt1, out + ro, 2048, 1024, 4096, b2, qb + ro, 0, 0, 1);
        }
    }
}

// Round 7
// 532.100 us; speedup vs baseline: 1.2369x; 1.0580x over previous
//
#include <hip/hip_runtime.h>
#include <stdint.h>
#include <stddef.h>

typedef unsigned short u16;
typedef u16 u16x4 __attribute__((ext_vector_type(4)));
typedef u16 u16x8 __attribute__((ext_vector_type(8)));
typedef __bf16 bf16x8 __attribute__((ext_vector_type(8)));
typedef float f32x4 __attribute__((ext_vector_type(4)));

__device__ __forceinline__ float b2f(u16 u) {
    return __uint_as_float(((unsigned)u) << 16);
}
__device__ __forceinline__ u16 f2b(float f) {
    unsigned u = __float_as_uint(f);
    u += 0x7FFF + ((u >> 16) & 1);   // round-to-nearest-even
    return (u16)(u >> 16);
}
__device__ __forceinline__ bf16x8 bcast(u16x8 v) { return __builtin_bit_cast(bf16x8, v); }
__device__ __forceinline__ f32x4 mfma16(bf16x8 a, bf16x8 b, f32x4 c) {
    return __builtin_amdgcn_mfma_f32_16x16x32_bf16(a, b, c, 0, 0, 0);
}
typedef const __attribute__((address_space(1))) void* gas1;
typedef __attribute__((address_space(3))) void* las3;
__device__ __forceinline__ void gload_lds16(const void* g, void* l) {
    __builtin_amdgcn_global_load_lds((gas1)g, (las3)l, 16, 0, 0);
}

// DPP row_ror:N (rotate within 16-lane row) — VALU cross-lane, no LDS.
#define DPP_ROR_F32(x, N) __builtin_bit_cast(float, __builtin_amdgcn_update_dpp( \
    __builtin_bit_cast(int, (x)), __builtin_bit_cast(int, (x)), 0x120 + (N), 0xf, 0xf, false))
__device__ __forceinline__ float red_max16(float x) {
    x = fmaxf(x, DPP_ROR_F32(x, 8));
    x = fmaxf(x, DPP_ROR_F32(x, 4));
    x = fmaxf(x, DPP_ROR_F32(x, 2));
    x = fmaxf(x, DPP_ROR_F32(x, 1));
    return x;
}
__device__ __forceinline__ float red_add16(float x) {
    x += DPP_ROR_F32(x, 8);
    x += DPP_ROR_F32(x, 4);
    x += DPP_ROR_F32(x, 2);
    x += DPP_ROR_F32(x, 1);
    return x;
}

// ---------------- transpose + f32->bf16: out[C][R] = bf16(in[R][C]) ----------
__global__ __launch_bounds__(256) void transpose_k(const float* __restrict__ in,
                                                   u16* __restrict__ out,
                                                   int R, int C) {
    __shared__ u16 t[32][33];
    int x = blockIdx.x * 32 + threadIdx.x;
    int y0 = blockIdx.y * 32;
#pragma unroll
    for (int j = threadIdx.y; j < 32; j += 8)
        t[j][threadIdx.x] = f2b(in[(size_t)(y0 + j) * C + x]);
    __syncthreads();
    int xo = y0 + threadIdx.x;
    int yo0 = blockIdx.x * 32;
#pragma unroll
    for (int j = threadIdx.y; j < 32; j += 8)
        out[(size_t)(yo0 + j) * R + xo] = t[threadIdx.x][j];
}

// ---------------- layernorm over D=1024, one block per row -------------------
__global__ __launch_bounds__(256) void ln_k(const void* __restrict__ x,
                                            const float* __restrict__ g,
                                            const float* __restrict__ b,
                                            u16* __restrict__ y,
                                            int x_f32) {
    const int row = blockIdx.x;
    const size_t ro = (size_t)row * 1024;
    float v[4], s = 0.0f, ss = 0.0f;
#pragma unroll
    for (int i = 0; i < 4; ++i) {
        size_t idx = ro + threadIdx.x + i * 256;
        float f = x_f32 ? ((const float*)x)[idx] : b2f(((const u16*)x)[idx]);
        v[i] = f; s += f; ss += f * f;
    }
#pragma unroll
    for (int off = 32; off; off >>= 1) {
        s += __shfl_down(s, off);
        ss += __shfl_down(ss, off);
    }
    __shared__ float red[2][4];
    int wave = threadIdx.x >> 6, lane = threadIdx.x & 63;
    if (lane == 0) { red[0][wave] = s; red[1][wave] = ss; }
    __syncthreads();
    s = red[0][0] + red[0][1] + red[0][2] + red[0][3];
    ss = red[1][0] + red[1][1] + red[1][2] + red[1][3];
    float mean = s * (1.0f / 1024.0f);
    float var = ss * (1.0f / 1024.0f) - mean * mean;
    float inv = rsqrtf(var + 1e-5f);
#pragma unroll
    for (int i = 0; i < 4; ++i) {
        int c = threadIdx.x + i * 256;
        float o = (v[i] - mean) * inv * g[c] + b[c];
        y[ro + c] = f2b(o);
    }
}

// ---------------- 128x256 GEMM core (race-free schedule, r4) -----------------
// BM=128, BN=256, BK=64, 512 thr = 8 waves (2Mx4N), wave tile 64x64 = acc[4][4].
// LDS 96 KiB: A dbuf 2x16 KB @0; B dbuf 2x32 KB @32768. T2 swizzle via
// inverse-swizzled global source (linear gload_lds dest) + swizzled ds_read.
// SAFE schedule: issue ALL 6 loads of tile t+1 at the TOP of iteration t;
// consume tile t (~1500 LDS-pipe cyc) in between; vmcnt(0) only at iteration
// end — issue-to-wait distance >= HBM latency, so the drain is nearly free.
// ONE barrier per K-tile.
__device__ __forceinline__ void gemm128_core(const u16* __restrict__ A,
                                             const u16* __restrict__ Bt,
                                             const int Ksz, const int m0,
                                             const int n0, u16* lds,
                                             f32x4 (&acc)[4][4]) {
    char* ldsb = (char*)lds;
    const int tid = threadIdx.x;
    const int w = tid >> 6, lane = tid & 63;
    const int quad = lane >> 4, l16 = lane & 15;
    const int wr = w >> 2, wc = w & 3;
    const int rS = w * 8 + (lane >> 3);
    const int cS = ((lane & 7) ^ (lane >> 3)) * 8;
    const int dstW = w * 1024;
    const int xo = (l16 & 7) << 4;
    const int co0 = (quad * 16) ^ xo;
    const int co1 = (64 + quad * 16) ^ xo;
    const int aoffB = wr * 8192 + l16 * 128;
    const int boffB = wc * 8192 + l16 * 128;
    const u16* pA = A + (size_t)(m0 + rS) * Ksz + cS;
    const u16* pB = Bt + (size_t)(n0 + rS) * Ksz + cS;
    const int nK = Ksz >> 6;
    const size_t rstep = (size_t)64 * Ksz;

#define STG_A(dd, kt) do { \
    const u16* _s = pA + (size_t)(kt) * 64; \
    char* _d = ldsb + (dd) * 16384 + dstW; \
    gload_lds16(_s, _d); \
    gload_lds16(_s + rstep, _d + 8192); \
} while (0)
#define STG_B(dd, h, kt) do { \
    const u16* _s = pB + (size_t)((h) * 128) * Ksz + (kt) * 64; \
    char* _d = ldsb + 32768 + (dd) * 32768 + (h) * 16384 + dstW; \
    gload_lds16(_s, _d); \
    gload_lds16(_s + rstep, _d + 8192); \
} while (0)

    bf16x8 af[2][4], bg[2][2][2];   // af[kk][mi], bg[nh][kk][n2]

#define LDA128() do { \
    _Pragma("unroll") for (int mi = 0; mi < 4; ++mi) { \
        af[0][mi] = bcast(*(const u16x8*)(ldsA + mi * 2048 + co0)); \
        af[1][mi] = bcast(*(const u16x8*)(ldsA + mi * 2048 + co1)); \
    } \
} while (0)
#define LDB128(nh) do { \
    _Pragma("unroll") for (int n2 = 0; n2 < 2; ++n2) { \
        bg[(nh)][0][n2] = bcast(*(const u16x8*)(ldsBp + ((nh) * 2 + n2) * 2048 + co0)); \
        bg[(nh)][1][n2] = bcast(*(const u16x8*)(ldsBp + ((nh) * 2 + n2) * 2048 + co1)); \
    } \
} while (0)
#define QUAD128(nh) do { \
    _Pragma("unroll") for (int mi = 0; mi < 4; ++mi) \
    _Pragma("unroll") for (int n2 = 0; n2 < 2; ++n2) { \
        acc[mi][(nh) * 2 + n2] = mfma16(af[0][mi], bg[(nh)][0][n2], acc[mi][(nh) * 2 + n2]); \
        acc[mi][(nh) * 2 + n2] = mfma16(af[1][mi], bg[(nh)][1][n2], acc[mi][(nh) * 2 + n2]); \
    } \
} while (0)

    // prologue: tile 0 (6 loads), drain, publish
    STG_A(0, 0); STG_B(0, 0, 0); STG_B(0, 1, 0);
    asm volatile("s_waitcnt vmcnt(0)" ::: "memory");
    __builtin_amdgcn_s_barrier();
    asm volatile("" ::: "memory");      // keep later ops below the barrier

    for (int t = 0; t < nK; ++t) {
        const int d = t & 1, e = d ^ 1;
        const char* ldsA = ldsb + d * 16384 + aoffB;
        const char* ldsBp = ldsb + 32768 + d * 32768 + boffB;
        // issue ALL of tile t+1 into nxt (fully retired since last barrier)
        if (t + 1 < nK) { STG_A(e, t + 1); STG_B(e, 0, t + 1); STG_B(e, 1, t + 1); }
        // phase A
        LDA128(); LDB128(0);
        asm volatile("s_waitcnt lgkmcnt(0)" ::: "memory");
        __builtin_amdgcn_s_setprio(1);
        QUAD128(0);
        __builtin_amdgcn_s_setprio(0);
        // phase B
        LDB128(1);
        asm volatile("s_waitcnt lgkmcnt(0)" ::: "memory");
        __builtin_amdgcn_s_setprio(1);
        QUAD128(1);
        __builtin_amdgcn_s_setprio(0);
        // tile t+1 landed (issued ~1 iteration ago -> usually zero stall)
        asm volatile("s_waitcnt vmcnt(0)" ::: "memory");
        __builtin_amdgcn_s_barrier();
        asm volatile("" ::: "memory");
    }
#undef STG_A
#undef STG_B
#undef LDA128
#undef LDB128
#undef QUAD128
}

// ---------------- gemm128 with fused epilogue --------------------------------
// bf16 outputs: per-wave LDS repack (64x72 u16 patch, private -> no barrier)
// then full-128B-line streaming stores (kills 2.4x write amplification).
// f32 outputs: direct scatter (64B runs, measured non-amplifying).
__global__ __launch_bounds__(512, 2) void gemm128(const u16* __restrict__ A,
                                                  const u16* __restrict__ Bt,
                                                  void* __restrict__ Cout,
                                                  int M, int N, int K,
                                                  const float* __restrict__ bias,
                                                  const void* __restrict__ resid,
                                                  int relu, int resid_f32, int out_f32) {
    (void)M;
    __shared__ __attribute__((aligned(16))) u16 lds[49152];
    f32x4 acc[4][4] = {};
    const int m0 = blockIdx.y * 128, n0 = blockIdx.x * 256;
    gemm128_core(A, Bt, K, m0, n0, lds, acc);
    const int tid = threadIdx.x;
    const int w = tid >> 6, lane = tid & 63;
    const int quad = lane >> 4, l16 = lane & 15;
    const int wr = w >> 2, wc = w & 3;
    const int row0 = m0 + wr * 64;
    if (out_f32) {
#pragma unroll
        for (int nj = 0; nj < 4; ++nj) {
            const int col = n0 + wc * 64 + nj * 16 + l16;
            const float bv = bias ? bias[col] : 0.0f;
#pragma unroll
            for (int mi = 0; mi < 4; ++mi) {
#pragma unroll
                for (int r = 0; r < 4; ++r) {
                    const size_t idx = (size_t)(row0 + mi * 16 + quad * 4 + r) * N + col;
                    float val = acc[mi][nj][r] + bv;
                    if (resid)
                        val += resid_f32 ? ((const float*)resid)[idx]
                                         : b2f(((const u16*)resid)[idx]);
                    if (relu) val = fmaxf(val, 0.0f);
                    ((float*)Cout)[idx] = val;
                }
            }
        }
    } else {
        u16* patch = &lds[w * 4608];       // 64 rows x 72 u16 (144B stride)
#pragma unroll
        for (int nj = 0; nj < 4; ++nj) {
            const int col = n0 + wc * 64 + nj * 16 + l16;
            const float bv = bias ? bias[col] : 0.0f;
#pragma unroll
            for (int mi = 0; mi < 4; ++mi) {
#pragma unroll
                for (int r = 0; r < 4; ++r) {
                    const int lr = mi * 16 + quad * 4 + r;
                    float val = acc[mi][nj][r] + bv;
                    if (resid) {
                        const size_t idx = (size_t)(row0 + lr) * N + col;
                        val += resid_f32 ? ((const float*)resid)[idx]
                                         : b2f(((const u16*)resid)[idx]);
                    }
                    if (relu) val = fmaxf(val, 0.0f);
                    patch[lr * 72 + nj * 16 + l16] = f2b(val);
                }
            }
        }
        asm volatile("s_waitcnt lgkmcnt(0)" ::: "memory");
        const int pr = lane >> 3, pc = (lane & 7) * 8;
        u16* gout = (u16*)Cout + (size_t)row0 * N + n0 + wc * 64;
#pragma unroll
        for (int p = 0; p < 8; ++p) {
            u16x8 v = *(const u16x8*)&patch[(p * 8 + pr) * 72 + pc];
            *(u16x8*)&gout[(size_t)(p * 8 + pr) * N + pc] = v;
        }
    }
}

// ---------------- fused QKV GEMM (128x256): [8192 x 3072] --------------------
// bx 0-3 = q, 4-7 = k, 8-11 = v (v written head-transposed [B*H][64][1024]).
// All outputs via per-wave LDS repack -> full-line stores (vT scatter was 16x
// write-amplified: 8B runs at 2KB stride).
__global__ __launch_bounds__(512, 2) void gemm128_qkv(const u16* __restrict__ A,
                                                      const u16* __restrict__ Bt,
                                                      u16* __restrict__ qb,
                                                      u16* __restrict__ kb,
                                                      u16* __restrict__ vbT) {
    __shared__ __attribute__((aligned(16))) u16 lds[49152];
    f32x4 acc[4][4] = {};
    const int m0 = blockIdx.y * 128, n0 = blockIdx.x * 256;
    gemm128_core(A, Bt, 1024, m0, n0, lds, acc);
    const int tid = threadIdx.x;
    const int w = tid >> 6, lane = tid & 63;
    const int quad = lane >> 4, l16 = lane & 15;
    const int wr = w >> 2, wc = w & 3;
    const int row0 = m0 + wr * 64;
    const int tens = blockIdx.x >> 2;                 // 0=q, 1=k, 2=v
    const int nbase = (blockIdx.x & 3) * 256 + wc * 64;
    u16* patch = &lds[w * 4608];                      // 64 x 72 u16
    const int pr = lane >> 3, pc = (lane & 7) * 8;
    if (tens < 2) {
        u16* dst = tens ? kb : qb;
#pragma unroll
        for (int mi = 0; mi < 4; ++mi)
#pragma unroll
            for (int nj = 0; nj < 4; ++nj)
#pragma unroll
                for (int r = 0; r < 4; ++r)
                    patch[(mi * 16 + quad * 4 + r) * 72 + nj * 16 + l16] =
                        f2b(acc[mi][nj][r]);
        asm volatile("s_waitcnt lgkmcnt(0)" ::: "memory");
        u16* gout = dst + (size_t)row0 * 1024 + nbase;
#pragma unroll
        for (int p = 0; p < 8; ++p) {
            u16x8 v = *(const u16x8*)&patch[(p * 8 + pr) * 72 + pc];
            *(u16x8*)&gout[(size_t)(p * 8 + pr) * 1024 + pc] = v;
        }
    } else {
        // patch holds [d 0..63][t 0..63]: d = nj*16+l16, t = mi*16+quad*4+r
#pragma unroll
        for (int mi = 0; mi < 4; ++mi)
#pragma unroll
            for (int nj = 0; nj < 4; ++nj)
#pragma unroll
                for (int r = 0; r < 4; ++r)
                    patch[(nj * 16 + l16) * 72 + mi * 16 + quad * 4 + r] =
                        f2b(acc[mi][nj][r]);
        asm volatile("s_waitcnt lgkmcnt(0)" ::: "memory");
        const int b = row0 >> 10, t0 = row0 & 1023;
        const int h = nbase >> 6;                     // head index 0..15
        u16* gout = vbT + (((size_t)(b * 16 + h) * 64) << 10) + t0;
#pragma unroll
        for (int p = 0; p < 8; ++p) {
            u16x8 v = *(const u16x8*)&patch[(p * 8 + pr) * 72 + pc];
            *(u16x8*)&gout[((size_t)(p * 8 + pr) << 10) + pc] = v;
        }
    }
}

// ---------------- causal flash attention v4 ----------------------------------
// r5: (1) complementary q-tile pairing — block bx handles qt=7-bx then qt=bx;
// njt sums to 18 for every block -> perfect load balance (was 8x imbalance,
// 12.8% occupancy). Grid (4,128)=512 blocks = exactly 2/CU.
// (2) skip-rescale when running max didn't grow (alpha==1.0 exactly -> O-rescale
// and l-fma are identities; bit-exact skip, wave-uniform branch).
// (3) causal masking only on diagonal tiles (jt >= 2*qt); interior tiles skip
// 32 cmp/cndmask per lane.
__global__ __launch_bounds__(256) void attn_k(const u16* __restrict__ q,
                                              const u16* __restrict__ k,
                                              const u16* __restrict__ vt,
                                              u16* __restrict__ att) {
    __shared__ __attribute__((aligned(16))) u16 Ks[64][72];
    __shared__ __attribute__((aligned(16))) u16 Vts[64][72];   // [dim][key]
    __shared__ __attribute__((aligned(16))) u16 QP[128 * 72];  // Qs then Ps
    const int bh = blockIdx.y;
    const int bb = bh >> 4, hd = bh & 15;
    const size_t base  = (size_t)bb * 1024 * 1024 + (size_t)hd * 64;
    const size_t vbase = (size_t)bh << 16;
    const int tid = threadIdx.x;
    const int w = tid >> 6, lane = tid & 63;
    const int quad = lane >> 4, l16 = lane & 15;
    u16* Ps = &QP[(w * 32) * 72];

    for (int half = 0; half < 2; ++half) {
        const int qt = half ? blockIdx.x : 7 - blockIdx.x;
        const int q0 = qt * 128;
        __syncthreads();   // prev half's LDS reads fully retired

#pragma unroll
        for (int it = 0; it < 4; ++it) {
            int f = it * 256 + tid;
            int r = f >> 3, c8 = (f & 7) * 8;
            *(u16x8*)&QP[r * 72 + c8] = *(const u16x8*)(q + base + (size_t)(q0 + r) * 1024 + c8);
        }
        __syncthreads();
        bf16x8 qf[2][2];
#pragma unroll
        for (int qi = 0; qi < 2; ++qi)
#pragma unroll
            for (int ks = 0; ks < 2; ++ks)
                qf[qi][ks] = bcast(*(const u16x8*)&QP[(w * 32 + qi * 16 + l16) * 72 + ks * 32 + quad * 8]);

        f32x4 oacc[2][4] = {};
        float mrow[2][4], lrow[2][4];
#pragma unroll
        for (int qi = 0; qi < 2; ++qi)
#pragma unroll
            for (int r = 0; r < 4; ++r) { mrow[qi][r] = -1e30f; lrow[qi][r] = 0.0f; }

        const int njt = qt * 2 + 2;
        for (int jt = 0; jt < njt; ++jt) {
            const int j0 = jt * 64;
#pragma unroll
            for (int it = 0; it < 2; ++it) {
                int f = it * 256 + tid;
                int r = f >> 3, c8 = (f & 7) * 8;
                *(u16x8*)&Ks[r][c8]  = *(const u16x8*)(k  + base  + (size_t)(j0 + r) * 1024 + c8);
                *(u16x8*)&Vts[r][c8] = *(const u16x8*)(vt + vbase + (size_t)r * 1024 + j0 + c8);
            }
            __syncthreads();

            // S = Q K^T
            f32x4 s[2][4] = {};
#pragma unroll
            for (int kj = 0; kj < 4; ++kj) {
                bf16x8 b0 = bcast(*(const u16x8*)&Ks[kj * 16 + l16][quad * 8]);
                bf16x8 b1 = bcast(*(const u16x8*)&Ks[kj * 16 + l16][32 + quad * 8]);
#pragma unroll
                for (int qi = 0; qi < 2; ++qi) {
                    s[qi][kj] = mfma16(qf[qi][0], b0, s[qi][kj]);
                    s[qi][kj] = mfma16(qf[qi][1], b1, s[qi][kj]);
                }
            }

            // ---- phase 1: scale (+mask only on diagonal tiles), in-lane max
            float tmax[2][4], alpha[2][4], rs[2][4];
            if (jt >= 2 * qt) {
#pragma unroll
                for (int qi = 0; qi < 2; ++qi)
#pragma unroll
                    for (int r = 0; r < 4; ++r) {
                        const int qrow = q0 + w * 32 + qi * 16 + quad * 4 + r;
                        float tm = -1e30f;
#pragma unroll
                        for (int kj = 0; kj < 4; ++kj) {
                            const int col = j0 + kj * 16 + l16;
                            float sv = s[qi][kj][r] * 0.03125f;
                            sv = (col > qrow) ? -1e30f : sv;
                            s[qi][kj][r] = sv;
                            tm = fmaxf(tm, sv);
                        }
                        tmax[qi][r] = tm;
                    }
            } else {
#pragma unroll
                for (int qi = 0; qi < 2; ++qi)
#pragma unroll
                    for (int r = 0; r < 4; ++r) {
                        float tm = -1e30f;
#pragma unroll
                        for (int kj = 0; kj < 4; ++kj) {
                            float sv = s[qi][kj][r] * 0.03125f;
                            s[qi][kj][r] = sv;
                            tm = fmaxf(tm, sv);
                        }
                        tmax[qi][r] = tm;
                    }
            }
            // ---- phase 2: 16-lane DPP max ----------------------------------
#pragma unroll
            for (int qi = 0; qi < 2; ++qi)
#pragma unroll
                for (int r = 0; r < 4; ++r)
                    tmax[qi][r] = red_max16(tmax[qi][r]);
            // ---- phase 3: rescale decision (bit-exact skip when alpha==1) --
            int grow = 0;
#pragma unroll
            for (int qi = 0; qi < 2; ++qi)
#pragma unroll
                for (int r = 0; r < 4; ++r)
                    grow |= (tmax[qi][r] > mrow[qi][r]) ? 1 : 0;
            const bool rescale = __any(grow);
            if (rescale) {
#pragma unroll
                for (int qi = 0; qi < 2; ++qi)
#pragma unroll
                    for (int r = 0; r < 4; ++r) {
                        float mnew = fmaxf(mrow[qi][r], tmax[qi][r]);
                        alpha[qi][r] = __expf(mrow[qi][r] - mnew);
                        mrow[qi][r] = mnew;
                    }
            }
            // ---- phase 3b: exp, in-lane sum --------------------------------
#pragma unroll
            for (int qi = 0; qi < 2; ++qi)
#pragma unroll
                for (int r = 0; r < 4; ++r) {
                    const float m = mrow[qi][r];
                    float accp = 0.0f;
#pragma unroll
                    for (int kj = 0; kj < 4; ++kj) {
                        float p = __expf(s[qi][kj][r] - m);
                        s[qi][kj][r] = p;
                        accp += p;
                    }
                    rs[qi][r] = accp;
                }
            // ---- phase 4: 16-lane DPP sum ----------------------------------
#pragma unroll
            for (int qi = 0; qi < 2; ++qi)
#pragma unroll
                for (int r = 0; r < 4; ++r)
                    rs[qi][r] = red_add16(rs[qi][r]);
            // ---- phase 5: l update, O rescale (skipped when alpha==1) ------
            if (rescale) {
#pragma unroll
                for (int qi = 0; qi < 2; ++qi)
#pragma unroll
                    for (int r = 0; r < 4; ++r) {
                        lrow[qi][r] = lrow[qi][r] * alpha[qi][r] + rs[qi][r];
#pragma unroll
                        for (int oj = 0; oj < 4; ++oj) oacc[qi][oj][r] *= alpha[qi][r];
                    }
            } else {
#pragma unroll
                for (int qi = 0; qi < 2; ++qi)
#pragma unroll
                    for (int r = 0; r < 4; ++r)
                        lrow[qi][r] += rs[qi][r];
            }
            // ---- phase 6: P -> LDS (batched) -------------------------------
#pragma unroll
            for (int qi = 0; qi < 2; ++qi)
#pragma unroll
                for (int r = 0; r < 4; ++r)
#pragma unroll
                    for (int kj = 0; kj < 4; ++kj)
                        Ps[(qi * 16 + quad * 4 + r) * 72 + kj * 16 + l16] = f2b(s[qi][kj][r]);

            // O += P V
#pragma unroll
            for (int ks = 0; ks < 2; ++ks) {
                bf16x8 a0 = bcast(*(const u16x8*)&Ps[(l16) * 72 + ks * 32 + quad * 8]);
                bf16x8 a1 = bcast(*(const u16x8*)&Ps[(16 + l16) * 72 + ks * 32 + quad * 8]);
#pragma unroll
                for (int oj = 0; oj < 4; ++oj) {
                    bf16x8 bv = bcast(*(const u16x8*)&Vts[oj * 16 + l16][ks * 32 + quad * 8]);
                    oacc[0][oj] = mfma16(a0, bv, oacc[0][oj]);
                    oacc[1][oj] = mfma16(a1, bv, oacc[1][oj]);
                }
            }
            __syncthreads();
        }
#pragma unroll
        for (int qi = 0; qi < 2; ++qi)
#pragma unroll
            for (int oj = 0; oj < 4; ++oj)
#pragma unroll
                for (int r = 0; r < 4; ++r) {
                    int row = q0 + w * 32 + qi * 16 + quad * 4 + r;
                    float o = oacc[qi][oj][r] / lrow[qi][r];
                    att[base + (size_t)row * 1024 + oj * 16 + l16] = f2b(o);
                }
    }
}

// ---------------- launch ----------------
extern "C" void kernel_launch(void* const* d_in, const int* in_sizes, int n_in,
                              void* d_out, int out_size, void* d_ws, size_t ws_size,
                              hipStream_t stream) {
    (void)in_sizes; (void)n_in; (void)out_size;
    const float* x   = (const float*)d_in[0];
    const float* Wq  = (const float*)d_in[1];
    const float* Wk  = (const float*)d_in[2];
    const float* Wv  = (const float*)d_in[3];
    const float* Wo  = (const float*)d_in[4];
    const float* bo  = (const float*)d_in[5];
    const float* W1  = (const float*)d_in[6];
    const float* b1  = (const float*)d_in[7];
    const float* W2  = (const float*)d_in[8];
    const float* b2  = (const float*)d_in[9];
    const float* g1  = (const float*)d_in[10];
    const float* be1 = (const float*)d_in[11];
    const float* g2  = (const float*)d_in[12];
    const float* be2 = (const float*)d_in[13];
    float* out = (float*)d_out;

    u16* ws = (u16*)d_ws;
    const size_t MIO = 1024u * 1024u;
    u16* Wt0 = ws;                 // [4 MiO]
    u16* Wt1 = ws + 4 * MIO;       // [4 MiO]
    u16* qb  = ws + 8 * MIO;       // q, later x2 (bf16)
    u16* kb  = ws + 16 * MIO;      // k, later h2 (bf16)
    u16* vb  = ws + 24 * MIO;      // vbT, later FFN hidden (chunked path)
    u16* mid = ws + 32 * MIO;      // [8192][4096] full FFN hidden (if ws allows)
    u16* hb  = (u16*)d_out;        // bf16 scratch: ln1-out, then attn-out
    const int full_ffn = ws_size >= (size_t)64 * MIO * 2;

    dim3 tb32(32, 8);

    ln_k<<<8192, 256, 0, stream>>>(x, g1, be1, hb, 1);

    transpose_k<<<dim3(32, 32), tb32, 0, stream>>>(Wq, Wt0,           1024, 1024);
    transpose_k<<<dim3(32, 32), tb32, 0, stream>>>(Wk, Wt0 + 1 * MIO, 1024, 1024);
    transpose_k<<<dim3(32, 32), tb32, 0, stream>>>(Wv, Wt0 + 2 * MIO, 1024, 1024);
    gemm128_qkv<<<dim3(12, 64), 512, 0, stream>>>(hb, Wt0, qb, kb, vb);

    attn_k<<<dim3(4, 128), 256, 0, stream>>>(qb, kb, vb, hb);

    transpose_k<<<dim3(32, 32), tb32, 0, stream>>>(Wo, Wt1, 1024, 1024);
    gemm128<<<dim3(4, 64), 512, 0, stream>>>(hb, Wt1, qb, 8192, 1024, 1024, bo, x, 0, 1, 0);

    ln_k<<<8192, 256, 0, stream>>>(qb, g2, be2, kb, 0);

    transpose_k<<<dim3(128, 32), tb32, 0, stream>>>(W1, Wt0, 1024, 4096);
    transpose_k<<<dim3(32, 128), tb32, 0, stream>>>(W2, Wt1, 4096, 1024);
    if (full_ffn) {
        gemm128<<<dim3(16, 64), 512, 0, stream>>>(kb, Wt0, mid, 8192, 4096, 1024, b1, nullptr, 1, 0, 0);
        gemm128<<<dim3(4, 64), 512, 0, stream>>>(mid, Wt1, out, 8192, 1024, 4096, b2, qb, 0, 0, 1);
    } else {
        for (int c = 0; c < 4; ++c) {
            const size_t ro = (size_t)c * 2048 * 1024;
            gemm128<<<dim3(16, 16), 512, 0, stream>>>(kb + ro, Wt0, vb, 2048, 4096, 1024, b1, nullptr, 1, 0, 0);
            gemm128<<<dim3(4, 16), 512, 0, stream>>>(vb, Wt1, out + ro, 2048, 1024, 4096, b2, qb + ro, 0, 0, 1);
        }
    }
}

// Round 8
// 486.795 us; speedup vs baseline: 1.3520x; 1.0931x over previous
//
#include <hip/hip_runtime.h>
#include <stdint.h>
#include <stddef.h>

typedef unsigned short u16;
typedef u16 u16x4 __attribute__((ext_vector_type(4)));
typedef u16 u16x8 __attribute__((ext_vector_type(8)));
typedef __bf16 bf16x8 __attribute__((ext_vector_type(8)));
typedef float f32x4 __attribute__((ext_vector_type(4)));

__device__ __forceinline__ float b2f(u16 u) {
    return __uint_as_float(((unsigned)u) << 16);
}
__device__ __forceinline__ u16 f2b(float f) {
    unsigned u = __float_as_uint(f);
    u += 0x7FFF + ((u >> 16) & 1);   // round-to-nearest-even
    return (u16)(u >> 16);
}
__device__ __forceinline__ bf16x8 bcast(u16x8 v) { return __builtin_bit_cast(bf16x8, v); }
__device__ __forceinline__ f32x4 mfma16(bf16x8 a, bf16x8 b, f32x4 c) {
    return __builtin_amdgcn_mfma_f32_16x16x32_bf16(a, b, c, 0, 0, 0);
}
typedef const __attribute__((address_space(1))) void* gas1;
typedef __attribute__((address_space(3))) void* las3;
__device__ __forceinline__ void gload_lds16(const void* g, void* l) {
    __builtin_amdgcn_global_load_lds((gas1)g, (las3)l, 16, 0, 0);
}

// DPP row_ror:N (rotate within 16-lane row) — VALU cross-lane, no LDS.
#define DPP_ROR_F32(x, N) __builtin_bit_cast(float, __builtin_amdgcn_update_dpp( \
    __builtin_bit_cast(int, (x)), __builtin_bit_cast(int, (x)), 0x120 + (N), 0xf, 0xf, false))
__device__ __forceinline__ float red_max16(float x) {
    x = fmaxf(x, DPP_ROR_F32(x, 8));
    x = fmaxf(x, DPP_ROR_F32(x, 4));
    x = fmaxf(x, DPP_ROR_F32(x, 2));
    x = fmaxf(x, DPP_ROR_F32(x, 1));
    return x;
}
__device__ __forceinline__ float red_add16(float x) {
    x += DPP_ROR_F32(x, 8);
    x += DPP_ROR_F32(x, 4);
    x += DPP_ROR_F32(x, 2);
    x += DPP_ROR_F32(x, 1);
    return x;
}

// ---------------- transpose + f32->bf16: out[C][R] = bf16(in[R][C]) ----------
__global__ __launch_bounds__(256) void transpose_k(const float* __restrict__ in,
                                                   u16* __restrict__ out,
                                                   int R, int C) {
    __shared__ u16 t[32][33];
    int x = blockIdx.x * 32 + threadIdx.x;
    int y0 = blockIdx.y * 32;
#pragma unroll
    for (int j = threadIdx.y; j < 32; j += 8)
        t[j][threadIdx.x] = f2b(in[(size_t)(y0 + j) * C + x]);
    __syncthreads();
    int xo = y0 + threadIdx.x;
    int yo0 = blockIdx.x * 32;
#pragma unroll
    for (int j = threadIdx.y; j < 32; j += 8)
        out[(size_t)(yo0 + j) * R + xo] = t[threadIdx.x][j];
}

// ---------------- layernorm over D=1024, one block per row -------------------
__global__ __launch_bounds__(256) void ln_k(const void* __restrict__ x,
                                            const float* __restrict__ g,
                                            const float* __restrict__ b,
                                            u16* __restrict__ y,
                                            int x_f32) {
    const int row = blockIdx.x;
    const size_t ro = (size_t)row * 1024;
    float v[4], s = 0.0f, ss = 0.0f;
#pragma unroll
    for (int i = 0; i < 4; ++i) {
        size_t idx = ro + threadIdx.x + i * 256;
        float f = x_f32 ? ((const float*)x)[idx] : b2f(((const u16*)x)[idx]);
        v[i] = f; s += f; ss += f * f;
    }
#pragma unroll
    for (int off = 32; off; off >>= 1) {
        s += __shfl_down(s, off);
        ss += __shfl_down(ss, off);
    }
    __shared__ float red[2][4];
    int wave = threadIdx.x >> 6, lane = threadIdx.x & 63;
    if (lane == 0) { red[0][wave] = s; red[1][wave] = ss; }
    __syncthreads();
    s = red[0][0] + red[0][1] + red[0][2] + red[0][3];
    ss = red[1][0] + red[1][1] + red[1][2] + red[1][3];
    float mean = s * (1.0f / 1024.0f);
    float var = ss * (1.0f / 1024.0f) - mean * mean;
    float inv = rsqrtf(var + 1e-5f);
#pragma unroll
    for (int i = 0; i < 4; ++i) {
        int c = threadIdx.x + i * 256;
        float o = (v[i] - mean) * inv * g[c] + b[c];
        y[ro + c] = f2b(o);
    }
}

// ---------------- 128x128 GEMM core (r8: 2 blocks/CU) ------------------------
// BM=BN=128, BK=64, 512 thr = 8 waves (2Mx4N), wave tile 64x32 = acc[4][2].
// LDS 64 KiB: A dbuf 2x16 KB @0; B dbuf 2x16 KB @32768 -> TWO blocks/CU
// (r7 was 96 KB -> 1 block/CU; all 8 waves stalled together at the per-iter
// vmcnt(0) drain with nothing to overlap -> 3.9k cyc/K-tile vs ~400 pipe floor.
// Co-resident block computes through the other's drain: m114 mechanism.)
// Same race-free r4 schedule: stage ALL of tile t+1 at top of iter t into the
// buffer retired at the previous barrier; ONE barrier per K-tile.
__device__ __forceinline__ void gemm128_core(const u16* __restrict__ A,
                                             const u16* __restrict__ Bt,
                                             const int Ksz, const int m0,
                                             const int n0, u16* lds,
                                             f32x4 (&acc)[4][2]) {
    char* ldsb = (char*)lds;
    const int tid = threadIdx.x;
    const int w = tid >> 6, lane = tid & 63;
    const int quad = lane >> 4, l16 = lane & 15;
    const int wr = w >> 2, wc = w & 3;
    const int rS = w * 8 + (lane >> 3);
    const int cS = ((lane & 7) ^ (lane >> 3)) * 8;
    const int dstW = w * 1024;
    const int xo = (l16 & 7) << 4;
    const int co0 = (quad * 16) ^ xo;
    const int co1 = (64 + quad * 16) ^ xo;
    const int aoffB = wr * 8192 + l16 * 128;
    const int boffB = wc * 4096 + l16 * 128;
    const u16* pA = A + (size_t)(m0 + rS) * Ksz + cS;
    const u16* pB = Bt + (size_t)(n0 + rS) * Ksz + cS;
    const int nK = Ksz >> 6;
    const size_t rstep = (size_t)64 * Ksz;

#define STG_A(dd, kt) do { \
    const u16* _s = pA + (size_t)(kt) * 64; \
    char* _d = ldsb + (dd) * 16384 + dstW; \
    gload_lds16(_s, _d); \
    gload_lds16(_s + rstep, _d + 8192); \
} while (0)
#define STG_B(dd, kt) do { \
    const u16* _s = pB + (size_t)(kt) * 64; \
    char* _d = ldsb + 32768 + (dd) * 16384 + dstW; \
    gload_lds16(_s, _d); \
    gload_lds16(_s + rstep, _d + 8192); \
} while (0)

    bf16x8 af[2][4], bg[2][2];      // af[kk][mi], bg[kk][n2]

#define LDA128() do { \
    _Pragma("unroll") for (int mi = 0; mi < 4; ++mi) { \
        af[0][mi] = bcast(*(const u16x8*)(ldsA + mi * 2048 + co0)); \
        af[1][mi] = bcast(*(const u16x8*)(ldsA + mi * 2048 + co1)); \
    } \
} while (0)
#define LDB128(n2) do { \
    bg[0][n2] = bcast(*(const u16x8*)(ldsBp + (n2) * 2048 + co0)); \
    bg[1][n2] = bcast(*(const u16x8*)(ldsBp + (n2) * 2048 + co1)); \
} while (0)
#define QUAD128(n2) do { \
    _Pragma("unroll") for (int mi = 0; mi < 4; ++mi) { \
        acc[mi][n2] = mfma16(af[0][mi], bg[0][n2], acc[mi][n2]); \
        acc[mi][n2] = mfma16(af[1][mi], bg[1][n2], acc[mi][n2]); \
    } \
} while (0)

    // prologue: tile 0 (4 loads), drain, publish
    STG_A(0, 0); STG_B(0, 0);
    asm volatile("s_waitcnt vmcnt(0)" ::: "memory");
    __builtin_amdgcn_s_barrier();
    asm volatile("" ::: "memory");      // keep later ops below the barrier

    for (int t = 0; t < nK; ++t) {
        const int d = t & 1, e = d ^ 1;
        const char* ldsA = ldsb + d * 16384 + aoffB;
        const char* ldsBp = ldsb + 32768 + d * 16384 + boffB;
        // issue ALL of tile t+1 into nxt (fully retired since last barrier)
        if (t + 1 < nK) { STG_A(e, t + 1); STG_B(e, t + 1); }
        // phase A
        LDA128(); LDB128(0);
        asm volatile("s_waitcnt lgkmcnt(0)" ::: "memory");
        __builtin_amdgcn_s_setprio(1);
        QUAD128(0);
        __builtin_amdgcn_s_setprio(0);
        // phase B
        LDB128(1);
        asm volatile("s_waitcnt lgkmcnt(0)" ::: "memory");
        __builtin_amdgcn_s_setprio(1);
        QUAD128(1);
        __builtin_amdgcn_s_setprio(0);
        // tile t+1 landed (issued ~1 iteration ago); co-resident block
        // computes through this drain
        asm volatile("s_waitcnt vmcnt(0)" ::: "memory");
        __builtin_amdgcn_s_barrier();
        asm volatile("" ::: "memory");
    }
#undef STG_A
#undef STG_B
#undef LDA128
#undef LDB128
#undef QUAD128
}

// ---------------- gemm128 with fused epilogue --------------------------------
// bf16 outputs: block-level LDS patch [128][136] (reuses GEMM LDS after the
// final barrier) -> 256B fully-coalesced line stores.
// f32 outputs: direct scatter (64B runs, measured non-amplifying).
__global__ __launch_bounds__(512, 4) void gemm128(const u16* __restrict__ A,
                                                  const u16* __restrict__ Bt,
                                                  void* __restrict__ Cout,
                                                  int M, int N, int K,
                                                  const float* __restrict__ bias,
                                                  const void* __restrict__ resid,
                                                  int relu, int resid_f32, int out_f32) {
    (void)M;
    __shared__ __attribute__((aligned(16))) u16 lds[32768];
    f32x4 acc[4][2] = {};
    const int m0 = blockIdx.y * 128, n0 = blockIdx.x * 128;
    gemm128_core(A, Bt, K, m0, n0, lds, acc);
    const int tid = threadIdx.x;
    const int w = tid >> 6, lane = tid & 63;
    const int quad = lane >> 4, l16 = lane & 15;
    const int wr = w >> 2, wc = w & 3;
    if (out_f32) {
#pragma unroll
        for (int n2 = 0; n2 < 2; ++n2) {
            const int col = n0 + wc * 32 + n2 * 16 + l16;
            const float bv = bias ? bias[col] : 0.0f;
#pragma unroll
            for (int mi = 0; mi < 4; ++mi) {
#pragma unroll
                for (int r = 0; r < 4; ++r) {
                    const size_t idx = (size_t)(m0 + wr * 64 + mi * 16 + quad * 4 + r) * N + col;
                    float val = acc[mi][n2][r] + bv;
                    if (resid)
                        val += resid_f32 ? ((const float*)resid)[idx]
                                         : b2f(((const u16*)resid)[idx]);
                    if (relu) val = fmaxf(val, 0.0f);
                    ((float*)Cout)[idx] = val;
                }
            }
        }
    } else {
#pragma unroll
        for (int n2 = 0; n2 < 2; ++n2) {
            const int dcol = wc * 32 + n2 * 16 + l16;
            const int col = n0 + dcol;
            const float bv = bias ? bias[col] : 0.0f;
#pragma unroll
            for (int mi = 0; mi < 4; ++mi) {
#pragma unroll
                for (int r = 0; r < 4; ++r) {
                    const int lr = wr * 64 + mi * 16 + quad * 4 + r;
                    float val = acc[mi][n2][r] + bv;
                    if (resid) {
                        const size_t idx = (size_t)(m0 + lr) * N + col;
                        val += resid_f32 ? ((const float*)resid)[idx]
                                         : b2f(((const u16*)resid)[idx]);
                    }
                    if (relu) val = fmaxf(val, 0.0f);
                    lds[lr * 136 + dcol] = f2b(val);
                }
            }
        }
        __syncthreads();
        const int sr = tid >> 4, sc = (tid & 15) * 8;
        u16* gout = (u16*)Cout + (size_t)m0 * N + n0;
#pragma unroll
        for (int p = 0; p < 4; ++p) {
            const int rr = p * 32 + sr;
            u16x8 v = *(const u16x8*)&lds[rr * 136 + sc];
            *(u16x8*)&gout[(size_t)rr * N + sc] = v;
        }
    }
}

// ---------------- fused QKV GEMM (128x128): [8192 x 3072] --------------------
// bx 0-7 = q, 8-15 = k, 16-23 = v (v written head-transposed [B*H][64][1024]).
// All outputs via block LDS patch -> 256B coalesced line stores.
__global__ __launch_bounds__(512, 4) void gemm128_qkv(const u16* __restrict__ A,
                                                      const u16* __restrict__ Bt,
                                                      u16* __restrict__ qb,
                                                      u16* __restrict__ kb,
                                                      u16* __restrict__ vbT) {
    __shared__ __attribute__((aligned(16))) u16 lds[32768];
    f32x4 acc[4][2] = {};
    const int m0 = blockIdx.y * 128, n0 = blockIdx.x * 128;
    gemm128_core(A, Bt, 1024, m0, n0, lds, acc);
    const int tid = threadIdx.x;
    const int w = tid >> 6, lane = tid & 63;
    const int quad = lane >> 4, l16 = lane & 15;
    const int wr = w >> 2, wc = w & 3;
    const int tens = blockIdx.x >> 3;                 // 0=q, 1=k, 2=v
    const int nbase = (blockIdx.x & 7) * 128;
    const int sr = tid >> 4, sc = (tid & 15) * 8;
    if (tens < 2) {
        u16* dst = tens ? kb : qb;
#pragma unroll
        for (int n2 = 0; n2 < 2; ++n2) {
            const int dcol = wc * 32 + n2 * 16 + l16;
#pragma unroll
            for (int mi = 0; mi < 4; ++mi)
#pragma unroll
                for (int r = 0; r < 4; ++r)
                    lds[(wr * 64 + mi * 16 + quad * 4 + r) * 136 + dcol] =
                        f2b(acc[mi][n2][r]);
        }
        __syncthreads();
        u16* gout = dst + (size_t)m0 * 1024 + nbase;
#pragma unroll
        for (int p = 0; p < 4; ++p) {
            const int rr = p * 32 + sr;
            u16x8 v = *(const u16x8*)&lds[rr * 136 + sc];
            *(u16x8*)&gout[(size_t)rr * 1024 + sc] = v;
        }
    } else {
        // transposed patch: lds[d][t], d = local col, t = local row
#pragma unroll
        for (int n2 = 0; n2 < 2; ++n2) {
            const int dcol = wc * 32 + n2 * 16 + l16;
#pragma unroll
            for (int mi = 0; mi < 4; ++mi)
#pragma unroll
                for (int r = 0; r < 4; ++r)
                    lds[dcol * 136 + wr * 64 + mi * 16 + quad * 4 + r] =
                        f2b(acc[mi][n2][r]);
        }
        __syncthreads();
        const int b = m0 >> 10, t0 = m0 & 1023;
#pragma unroll
        for (int p = 0; p < 4; ++p) {
            const int dd = p * 32 + sr;
            const int h = (nbase + dd) >> 6, d6 = (nbase + dd) & 63;
            u16x8 v = *(const u16x8*)&lds[dd * 136 + sc];
            *(u16x8*)&vbT[(((size_t)(b * 16 + h) * 64 + d6) << 10) + t0 + sc] = v;
        }
    }
}

// ---------------- causal flash attention v4 ----------------------------------
// (1) complementary q-tile pairing — block bx handles qt=7-bx then qt=bx;
// njt sums to 18 for every block -> perfect load balance. Grid (4,128)=512
// blocks = exactly 2/CU. (2) bit-exact skip-rescale when running max didn't
// grow. (3) causal masking only on diagonal tiles (jt >= 2*qt).
__global__ __launch_bounds__(256) void attn_k(const u16* __restrict__ q,
                                              const u16* __restrict__ k,
                                              const u16* __restrict__ vt,
                                              u16* __restrict__ att) {
    __shared__ __attribute__((aligned(16))) u16 Ks[64][72];
    __shared__ __attribute__((aligned(16))) u16 Vts[64][72];   // [dim][key]
    __shared__ __attribute__((aligned(16))) u16 QP[128 * 72];  // Qs then Ps
    const int bh = blockIdx.y;
    const int bb = bh >> 4, hd = bh & 15;
    const size_t base  = (size_t)bb * 1024 * 1024 + (size_t)hd * 64;
    const size_t vbase = (size_t)bh << 16;
    const int tid = threadIdx.x;
    const int w = tid >> 6, lane = tid & 63;
    const int quad = lane >> 4, l16 = lane & 15;
    u16* Ps = &QP[(w * 32) * 72];

    for (int half = 0; half < 2; ++half) {
        const int qt = half ? blockIdx.x : 7 - blockIdx.x;
        const int q0 = qt * 128;
        __syncthreads();   // prev half's LDS reads fully retired

#pragma unroll
        for (int it = 0; it < 4; ++it) {
            int f = it * 256 + tid;
            int r = f >> 3, c8 = (f & 7) * 8;
            *(u16x8*)&QP[r * 72 + c8] = *(const u16x8*)(q + base + (size_t)(q0 + r) * 1024 + c8);
        }
        __syncthreads();
        bf16x8 qf[2][2];
#pragma unroll
        for (int qi = 0; qi < 2; ++qi)
#pragma unroll
            for (int ks = 0; ks < 2; ++ks)
                qf[qi][ks] = bcast(*(const u16x8*)&QP[(w * 32 + qi * 16 + l16) * 72 + ks * 32 + quad * 8]);

        f32x4 oacc[2][4] = {};
        float mrow[2][4], lrow[2][4];
#pragma unroll
        for (int qi = 0; qi < 2; ++qi)
#pragma unroll
            for (int r = 0; r < 4; ++r) { mrow[qi][r] = -1e30f; lrow[qi][r] = 0.0f; }

        const int njt = qt * 2 + 2;
        for (int jt = 0; jt < njt; ++jt) {
            const int j0 = jt * 64;
#pragma unroll
            for (int it = 0; it < 2; ++it) {
                int f = it * 256 + tid;
                int r = f >> 3, c8 = (f & 7) * 8;
                *(u16x8*)&Ks[r][c8]  = *(const u16x8*)(k  + base  + (size_t)(j0 + r) * 1024 + c8);
                *(u16x8*)&Vts[r][c8] = *(const u16x8*)(vt + vbase + (size_t)r * 1024 + j0 + c8);
            }
            __syncthreads();

            // S = Q K^T
            f32x4 s[2][4] = {};
#pragma unroll
            for (int kj = 0; kj < 4; ++kj) {
                bf16x8 b0 = bcast(*(const u16x8*)&Ks[kj * 16 + l16][quad * 8]);
                bf16x8 b1 = bcast(*(const u16x8*)&Ks[kj * 16 + l16][32 + quad * 8]);
#pragma unroll
                for (int qi = 0; qi < 2; ++qi) {
                    s[qi][kj] = mfma16(qf[qi][0], b0, s[qi][kj]);
                    s[qi][kj] = mfma16(qf[qi][1], b1, s[qi][kj]);
                }
            }

            // ---- phase 1: scale (+mask only on diagonal tiles), in-lane max
            float tmax[2][4], alpha[2][4], rs[2][4];
            if (jt >= 2 * qt) {
#pragma unroll
                for (int qi = 0; qi < 2; ++qi)
#pragma unroll
                    for (int r = 0; r < 4; ++r) {
                        const int qrow = q0 + w * 32 + qi * 16 + quad * 4 + r;
                        float tm = -1e30f;
#pragma unroll
                        for (int kj = 0; kj < 4; ++kj) {
                            const int col = j0 + kj * 16 + l16;
                            float sv = s[qi][kj][r] * 0.03125f;
                            sv = (col > qrow) ? -1e30f : sv;
                            s[qi][kj][r] = sv;
                            tm = fmaxf(tm, sv);
                        }
                        tmax[qi][r] = tm;
                    }
            } else {
#pragma unroll
                for (int qi = 0; qi < 2; ++qi)
#pragma unroll
                    for (int r = 0; r < 4; ++r) {
                        float tm = -1e30f;
#pragma unroll
                        for (int kj = 0; kj < 4; ++kj) {
                            float sv = s[qi][kj][r] * 0.03125f;
                            s[qi][kj][r] = sv;
                            tm = fmaxf(tm, sv);
                        }
                        tmax[qi][r] = tm;
                    }
            }
            // ---- phase 2: 16-lane DPP max ----------------------------------
#pragma unroll
            for (int qi = 0; qi < 2; ++qi)
#pragma unroll
                for (int r = 0; r < 4; ++r)
                    tmax[qi][r] = red_max16(tmax[qi][r]);
            // ---- phase 3: rescale decision (bit-exact skip when alpha==1) --
            int grow = 0;
#pragma unroll
            for (int qi = 0; qi < 2; ++qi)
#pragma unroll
                for (int r = 0; r < 4; ++r)
                    grow |= (tmax[qi][r] > mrow[qi][r]) ? 1 : 0;
            const bool rescale = __any(grow);
            if (rescale) {
#pragma unroll
                for (int qi = 0; qi < 2; ++qi)
#pragma unroll
                    for (int r = 0; r < 4; ++r) {
                        float mnew = fmaxf(mrow[qi][r], tmax[qi][r]);
                        alpha[qi][r] = __expf(mrow[qi][r] - mnew);
                        mrow[qi][r] = mnew;
                    }
            }
            // ---- phase 3b: exp, in-lane sum --------------------------------
#pragma unroll
            for (int qi = 0; qi < 2; ++qi)
#pragma unroll
                for (int r = 0; r < 4; ++r) {
                    const float m = mrow[qi][r];
                    float accp = 0.0f;
#pragma unroll
                    for (int kj = 0; kj < 4; ++kj) {
                        float p = __expf(s[qi][kj][r] - m);
                        s[qi][kj][r] = p;
                        accp += p;
                    }
                    rs[qi][r] = accp;
                }
            // ---- phase 4: 16-lane DPP sum ----------------------------------
#pragma unroll
            for (int qi = 0; qi < 2; ++qi)
#pragma unroll
                for (int r = 0; r < 4; ++r)
                    rs[qi][r] = red_add16(rs[qi][r]);
            // ---- phase 5: l update, O rescale (skipped when alpha==1) ------
            if (rescale) {
#pragma unroll
                for (int qi = 0; qi < 2; ++qi)
#pragma unroll
                    for (int r = 0; r < 4; ++r) {
                        lrow[qi][r] = lrow[qi][r] * alpha[qi][r] + rs[qi][r];
#pragma unroll
                        for (int oj = 0; oj < 4; ++oj) oacc[qi][oj][r] *= alpha[qi][r];
                    }
            } else {
#pragma unroll
                for (int qi = 0; qi < 2; ++qi)
#pragma unroll
                    for (int r = 0; r < 4; ++r)
                        lrow[qi][r] += rs[qi][r];
            }
            // ---- phase 6: P -> LDS (batched) -------------------------------
#pragma unroll
            for (int qi = 0; qi < 2; ++qi)
#pragma unroll
                for (int r = 0; r < 4; ++r)
#pragma unroll
                    for (int kj = 0; kj < 4; ++kj)
                        Ps[(qi * 16 + quad * 4 + r) * 72 + kj * 16 + l16] = f2b(s[qi][kj][r]);

            // O += P V
#pragma unroll
            for (int ks = 0; ks < 2; ++ks) {
                bf16x8 a0 = bcast(*(const u16x8*)&Ps[(l16) * 72 + ks * 32 + quad * 8]);
                bf16x8 a1 = bcast(*(const u16x8*)&Ps[(16 + l16) * 72 + ks * 32 + quad * 8]);
#pragma unroll
                for (int oj = 0; oj < 4; ++oj) {
                    bf16x8 bv = bcast(*(const u16x8*)&Vts[oj * 16 + l16][ks * 32 + quad * 8]);
                    oacc[0][oj] = mfma16(a0, bv, oacc[0][oj]);
                    oacc[1][oj] = mfma16(a1, bv, oacc[1][oj]);
                }
            }
            __syncthreads();
        }
#pragma unroll
        for (int qi = 0; qi < 2; ++qi)
#pragma unroll
            for (int oj = 0; oj < 4; ++oj)
#pragma unroll
                for (int r = 0; r < 4; ++r) {
                    int row = q0 + w * 32 + qi * 16 + quad * 4 + r;
                    float o = oacc[qi][oj][r] / lrow[qi][r];
                    att[base + (size_t)row * 1024 + oj * 16 + l16] = f2b(o);
                }
    }
}

// ---------------- launch ----------------
extern "C" void kernel_launch(void* const* d_in, const int* in_sizes, int n_in,
                              void* d_out, int out_size, void* d_ws, size_t ws_size,
                              hipStream_t stream) {
    (void)in_sizes; (void)n_in; (void)out_size;
    const float* x   = (const float*)d_in[0];
    const float* Wq  = (const float*)d_in[1];
    const float* Wk  = (const float*)d_in[2];
    const float* Wv  = (const float*)d_in[3];
    const float* Wo  = (const float*)d_in[4];
    const float* bo  = (const float*)d_in[5];
    const float* W1  = (const float*)d_in[6];
    const float* b1  = (const float*)d_in[7];
    const float* W2  = (const float*)d_in[8];
    const float* b2  = (const float*)d_in[9];
    const float* g1  = (const float*)d_in[10];
    const float* be1 = (const float*)d_in[11];
    const float* g2  = (const float*)d_in[12];
    const float* be2 = (const float*)d_in[13];
    float* out = (float*)d_out;

    u16* ws = (u16*)d_ws;
    const size_t MIO = 1024u * 1024u;
    u16* Wt0 = ws;                 // [4 MiO]
    u16* Wt1 = ws + 4 * MIO;       // [4 MiO]
    u16* qb  = ws + 8 * MIO;       // q, later x2 (bf16)
    u16* kb  = ws + 16 * MIO;      // k, later h2 (bf16)
    u16* vb  = ws + 24 * MIO;      // vbT, later FFN hidden (chunked path)
    u16* mid = ws + 32 * MIO;      // [8192][4096] full FFN hidden (if ws allows)
    u16* hb  = (u16*)d_out;        // bf16 scratch: ln1-out, then attn-out
    const int full_ffn = ws_size >= (size_t)64 * MIO * 2;

    dim3 tb32(32, 8);

    ln_k<<<8192, 256, 0, stream>>>(x, g1, be1, hb, 1);

    transpose_k<<<dim3(32, 32), tb32, 0, stream>>>(Wq, Wt0,           1024, 1024);
    transpose_k<<<dim3(32, 32), tb32, 0, stream>>>(Wk, Wt0 + 1 * MIO, 1024, 1024);
    transpose_k<<<dim3(32, 32), tb32, 0, stream>>>(Wv, Wt0 + 2 * MIO, 1024, 1024);
    gemm128_qkv<<<dim3(24, 64), 512, 0, stream>>>(hb, Wt0, qb, kb, vb);

    attn_k<<<dim3(4, 128), 256, 0, stream>>>(qb, kb, vb, hb);

    transpose_k<<<dim3(32, 32), tb32, 0, stream>>>(Wo, Wt1, 1024, 1024);
    gemm128<<<dim3(8, 64), 512, 0, stream>>>(hb, Wt1, qb, 8192, 1024, 1024, bo, x, 0, 1, 0);

    ln_k<<<8192, 256, 0, stream>>>(qb, g2, be2, kb, 0);

    transpose_k<<<dim3(128, 32), tb32, 0, stream>>>(W1, Wt0, 1024, 4096);
    transpose_k<<<dim3(32, 128), tb32, 0, stream>>>(W2, Wt1, 4096, 1024);
    if (full_ffn) {
        gemm128<<<dim3(32, 64), 512, 0, stream>>>(kb, Wt0, mid, 8192, 4096, 1024, b1, nullptr, 1, 0, 0);
        gemm128<<<dim3(8, 64), 512, 0, stream>>>(mid, Wt1, out, 8192, 1024, 4096, b2, qb, 0, 0, 1);
    } else {
        for (int c = 0; c < 4; ++c) {
            const size_t ro = (size_t)c * 2048 * 1024;
            gemm128<<<dim3(32, 16), 512, 0, stream>>>(kb + ro, Wt0, vb, 2048, 4096, 1024, b1, nullptr, 1, 0, 0);
            gemm128<<<dim3(8, 16), 512, 0, stream>>>(vb, Wt1, out + ro, 2048, 1024, 4096, b2, qb + ro, 0, 0, 1);
        }
    }
}